// Round 5
// baseline (149.558 us; speedup 1.0000x reference)
//
#include <hip/hip_runtime.h>
#include <math.h>

#define TT 512
#define NB 32
#define NRSTEP 200
#define KSC 14.4269504f          // 10 * log2(e); u = KSC * R
#define MAGICF 0x5CA1AB1E

// Schraudolph fast 2^a for a in [-5, 0] (verified R8/R10/R12/R15/R17)
#define SCHR_SCALE (-KSC * 8388608.0f)
#define SCHR_OFF   1064986823.0f         // 127*2^23 - 366393

typedef float float2v __attribute__((ext_vector_type(2)));

// ---- forced VOP3P packed f32 ops (dual-issue FP32, gfx90a+/gfx950) ----
__device__ __forceinline__ float2v pk_add(float2v a, float2v b) {
    float2v d;
    asm("v_pk_add_f32 %0, %1, %2" : "=v"(d) : "v"(a), "v"(b));
    return d;
}
__device__ __forceinline__ float2v pk_mul(float2v a, float2v b) {
    float2v d;
    asm("v_pk_mul_f32 %0, %1, %2" : "=v"(d) : "v"(a), "v"(b));
    return d;
}
__device__ __forceinline__ float2v pk_fma(float2v a, float2v b, float2v c) {
    float2v d;
    asm("v_pk_fma_f32 %0, %1, %2, %3" : "=v"(d) : "v"(a), "v"(b), "v"(c));
    return d;
}

// DPP wave_shr:1 — lane i <- lane i-1, lane 0 gets 0 (verified R5..R17)
__device__ __forceinline__ float dpp_up1_f(float x) {
    return __int_as_float(__builtin_amdgcn_update_dpp(
        0, __float_as_int(x), 0x138, 0xf, 0xf, false));
}
__device__ __forceinline__ int dpp_up1_i(int x) {
    return __builtin_amdgcn_update_dpp(0, x, 0x138, 0xf, 0xf, false);
}
__device__ __forceinline__ float rdlane_f(float v, int lane) {
    return __int_as_float(__builtin_amdgcn_readlane(__float_as_int(v), lane));
}
__device__ __forceinline__ float exp2i(int e) {   // 2^e, |e|<=126, no trans op
    return __int_as_float((e + 127) << 23);
}
// v_cndmask with an SGPR-pair mask built in SALU: m ? a : b  (R23)
__device__ __forceinline__ float sel_f(unsigned long long m, float a, float b) {
    float d;
    asm("v_cndmask_b32 %0, %1, %2, %3" : "=v"(d) : "v"(b), "v"(a), "s"(m));
    return d;
}
__device__ __forceinline__ int sel_i(unsigned long long m, int a, int b) {
    int d;
    asm("v_cndmask_b32 %0, %1, %2, %3" : "=v"(d) : "v"(b), "v"(a), "s"(m));
    return d;
}

// ---------------- Fused kernel: gather + HUX + stats + soft-DTW + finalize ----
// one block (one wave) per batch b; lane owns rows t = lane*8 .. lane*8+7
// DP: R15/R17-proven MONOLITHIC w-domain 2-group packed sweep, exact
// per-substep exponent tracking.
//
// *** DP LOOP DATAFLOW IS FROZEN. ***
// Failed restructurings, all with source-invisible cause (outputs 0-2 pass,
// dtw=inf):  R13/R14/R16 loop splits;  R20/R21 wdA-carry (algebraically
// bit-identical on paper, fails on HW — CONVICTED by R21 bisection).
// Do NOT add loop-carried values, do NOT replace the pW/pE delay line,
// do NOT split the 80-blk loop.
//
// R18: hot packed math forced to v_pk_* via inline asm; y-pipeline carries
// NEGATED y so the D-term is pk_add(x2, z2n) with no modifiers (bit-identical).
// R19: HUX forced to v_pk_*; wrap-rotate via one ds_bpermute; int4 lat_idx.
// R22: HUX max(v,1) dropped — v provably stays in [300,700] (convex updates,
//      kappa<=0.55), proven safe by R20/R21 outputs 0-2 passing.
// R23: (b)-retry — R21 bisection convicted (a) only; (b) SALU masks were
//      never isolated. pub/adopt selects now take SALU-built masks derived
//      from the uniform substep index s (vj0 VGPR arithmetic removed; mask
//      algebra verified at s=0,1,638,639). pW/pE delay line UNCHANGED.
//      Also: blk-loop unroll 2 + HUX unroll 4 (pure scheduling, no dataflow).
__global__ __launch_bounds__(64, 1) void fused_kernel(
    const float* __restrict__ pred_map,  // [B,1,T,128]
    const int*   __restrict__ lat_idx,   // [B,T]
    const float* __restrict__ omega,     // [B]
    const float* __restrict__ omni,      // [B,T]
    float*       __restrict__ out,       // v_out at [0, B*T), scalars after
    float*       __restrict__ ws)
{
    const int b    = blockIdx.x;
    const int lane = threadIdx.x;
    const int t0   = lane * 8;
    const bool lane0 = (lane == 0);

    // ---- gather v_in ----
    float v[8];
    const int4* li4 = (const int4*)(lat_idx + b * TT + t0);
    const int4 liA = li4[0];
    const int4 liB = li4[1];
    int li[8] = {liA.x, liA.y, liA.z, liA.w, liB.x, liB.y, liB.z, liB.w};
    const float* pm = pred_map + (size_t)b * TT * 128 + (size_t)t0 * 128;
    #pragma unroll
    for (int k = 0; k < 8; ++k) v[k] = pm[k * 128 + li[k]];

    // ---- HUX-f: 200 upwind steps, packed: W[i] = {v[i], v[i+4]} (R17) ----
    const float c = (float)(673089.75 / (2.0 * M_PI / 512.0)) * omega[b];
    const float2v c2 = {c, c};
    const float2v kM1 = {-1.0f, -1.0f};
    const float2v kTwo = {2.0f, 2.0f};
    const int rot = ((lane + 1) & 63) << 2;   // bpermute byte addr: lane i+1 mod 64
    float2v W[4];
    W[0].x = v[0]; W[0].y = v[4];
    W[1].x = v[1]; W[1].y = v[5];
    W[2].x = v[2]; W[2].y = v[6];
    W[3].x = v[3]; W[3].y = v[7];
    #pragma unroll 4
    for (int it = 0; it < NRSTEP; ++it) {
        // wrap-rotate: lane i <- old v[0] of lane i+1 (lane 63 <- lane 0).
        float vn = __int_as_float(__builtin_amdgcn_ds_bpermute(
            rot, __float_as_int(W[0].x)));

        // r = fastrcp(W) : magic + 1 Newton, all packed.
        // max(v,1) dropped: identity on [300,700] (proven safe, R20/R21).
        float2v g0, g1, g2, g3;
        g0.x = __int_as_float(0x7EF311C3 - __float_as_int(W[0].x));
        g0.y = __int_as_float(0x7EF311C3 - __float_as_int(W[0].y));
        g1.x = __int_as_float(0x7EF311C3 - __float_as_int(W[1].x));
        g1.y = __int_as_float(0x7EF311C3 - __float_as_int(W[1].y));
        g2.x = __int_as_float(0x7EF311C3 - __float_as_int(W[2].x));
        g2.y = __int_as_float(0x7EF311C3 - __float_as_int(W[2].y));
        g3.x = __int_as_float(0x7EF311C3 - __float_as_int(W[3].x));
        g3.y = __int_as_float(0x7EF311C3 - __float_as_int(W[3].y));
        float2v r0 = pk_mul(g0, pk_fma(pk_mul(W[0], g0), kM1, kTwo));
        float2v r1 = pk_mul(g1, pk_fma(pk_mul(W[1], g1), kM1, kTwo));
        float2v r2 = pk_mul(g2, pk_fma(pk_mul(W[2], g2), kM1, kTwo));
        float2v r3 = pk_mul(g3, pk_fma(pk_mul(W[3], g3), kM1, kTwo));

        float2v nb0 = W[1], nb1 = W[2], nb2 = W[3];
        float2v nb3; nb3.x = W[0].y; nb3.y = vn;

        // W += c2 * r * (nb - W)
        float2v d0 = pk_fma(W[0], kM1, nb0);
        float2v d1 = pk_fma(W[1], kM1, nb1);
        float2v d2 = pk_fma(W[2], kM1, nb2);
        float2v d3 = pk_fma(W[3], kM1, nb3);
        W[0] = pk_fma(pk_mul(r0, d0), c2, W[0]);
        W[1] = pk_fma(pk_mul(r1, d1), c2, W[1]);
        W[2] = pk_fma(pk_mul(r2, d2), c2, W[2]);
        W[3] = pk_fma(pk_mul(r3, d3), c2, W[3]);
    }
    v[0] = W[0].x; v[4] = W[0].y;
    v[1] = W[1].x; v[5] = W[1].y;
    v[2] = W[2].x; v[6] = W[2].y;
    v[3] = W[3].x; v[7] = W[3].y;

    // ---- write v_out ----
    float4* o4 = (float4*)(out + b * TT + t0);
    o4[0] = make_float4(v[0], v[1], v[2], v[3]);
    o4[1] = make_float4(v[4], v[5], v[6], v[7]);

    // ---- scaled series + per-b stats ----
    float x[8], y8[8], y8n[8];
    const float* om = omni + b * TT + t0;
    float sx = 0.f, syy0 = 0.f;
    #pragma unroll
    for (int k = 0; k < 8; ++k) {
        x[k]   = (om[k] - 200.0f) * 1e-3f;   // omni_scaled (rows)
        y8[k]  = (v[k] - 200.0f) * 1e-3f;    // v_out_scaled (cols)
        y8n[k] = -y8[k];                     // negated for the DP y-pipeline
        sx += x[k];
        syy0 += y8[k];
    }
    #pragma unroll
    for (int m = 1; m < 64; m <<= 1) {
        sx   += __shfl_xor(sx, m, 64);
        syy0 += __shfl_xor(syy0, m, 64);
    }
    const float mx = sx * (1.0f / 512.0f);
    const float my = syy0 * (1.0f / 512.0f);

    float sab = 0.f, ssq = 0.f, snum = 0.f, sxx = 0.f, spp = 0.f;
    #pragma unroll
    for (int k = 0; k < 8; ++k) {
        float d = y8[k] - x[k];
        sab += fabsf(d);
        ssq += d * d;
        float pc = y8[k] - my;
        float tc = x[k] - mx;
        snum += pc * tc;
        sxx  += tc * tc;
        spp  += pc * pc;
    }
    #pragma unroll
    for (int m = 1; m < 64; m <<= 1) {
        sab  += __shfl_xor(sab,  m, 64);
        ssq  += __shfl_xor(ssq,  m, 64);
        snum += __shfl_xor(snum, m, 64);
        sxx  += __shfl_xor(sxx,  m, 64);
        spp  += __shfl_xor(spp,  m, 64);
    }
    const float corr = snum / (sqrtf(spp) * sqrtf(sxx));

    // ---- soft-DTW, w-domain, 2-group packed, exact per-substep scales ----
    // (monolithic 80-blk loop — proven; z pipeline carries NEGATED y)
    float2v x2[4];
    #pragma unroll
    for (int i = 0; i < 4; ++i) { x2[i].x = x[i]; x2[i].y = x[i + 4]; }
    const float2v kS2 = {SCHR_SCALE, SCHR_SCALE};
    const float2v kO2 = {SCHR_OFF, SCHR_OFF};

    float2v P[4];
    #pragma unroll
    for (int k = 0; k < 4; ++k) P[k] = (float2v){0.0f, 0.0f};
    int   E = 0;
    float c7w = 0.0f; int c7E = 0;    // published boundary (B-tail, row 8l+7)
    float aT = 0.0f, aT2 = 0.0f;      // A-tail (row 8l+3) delay line -> B-chain
    float pW = 0.0f;  int pE = 0;     // lane l-1 B-tail, two substeps back
    const float adoptW = lane0 ? 1.0f : 0.0f;  // diag at adopt: origin / BIG

    // y pipeline (NEGATED): before substep s, zA(l) = -y[s-2l], zB(l) = -y[s-1-2l]
    float zA = lane0 ? y8n[0] : 0.0f;
    float zB = 0.0f;

    #pragma unroll 2
    for (int blk = 0; blk < 80; ++blk) {
        const int us  = blk < 63 ? blk : 63;
        const int us1 = blk < 62 ? blk + 1 : 63;   // readlane idx must be <= 63
        float f[8];
        f[0] = rdlane_f(y8n[1], us);
        f[1] = rdlane_f(y8n[2], us);
        f[2] = rdlane_f(y8n[3], us);
        f[3] = rdlane_f(y8n[4], us);
        f[4] = rdlane_f(y8n[5], us);
        f[5] = rdlane_f(y8n[6], us);
        f[6] = rdlane_f(y8n[7], us);
        f[7] = rdlane_f(y8n[0], us1);

        #pragma unroll
        for (int q = 0; q < 8; ++q) {
            const int s = blk * 8 + q;    // global substep (uniform -> SALU)

            float nW  = dpp_up1_f(c7w);   // lane l-1 B-tail at col j0 (scale nEc)
            int   nEc = dpp_up1_i(c7E);

            // D-factors (Schraudolph), forced v_pk_*: t = x + (-y) = pk_add
            float2v z2; z2.x = zA; z2.y = zB;
            float2v fsv[4];
            #pragma unroll
            for (int i = 0; i < 4; ++i) {
                float2v t  = pk_add(x2[i], z2);
                float2v t2 = pk_mul(t, t);
                float2v h  = pk_fma(t2, kS2, kO2);
                fsv[i].x = __int_as_float((int)h.x);
                fsv[i].y = __int_as_float((int)h.y);
            }

            // adopt: lane == s/2, even s only (s parity == q parity, so the
            // branch vanishes at compile time for odd q). SALU mask; the
            // pW/pE delay-line dataflow below is UNCHANGED (frozen).
            float wuA, wdA;
            if ((q & 1) == 0) {
                unsigned long long amask =
                    (s <= 126) ? (1ull << (s >> 1)) : 0ull;
                E   = sel_i(amask, nEc, E);        // adopt neighbor scale
                wuA = ldexpf(nW, E - nEc);         // up for A-head, our scale
                wdA = ldexpf(pW, E - pE);          // diag for A-head
                wdA = sel_f(amask, adoptW, wdA);   // col -1 = BIG; lane0 origin
            } else {
                wuA = ldexpf(nW, E - nEc);
                wdA = ldexpf(pW, E - pE);
            }

            float2v uc, dgn;
            uc.x  = wuA; uc.y  = aT;      // B-head up = own A-tail (s-1)
            dgn.x = wdA; dgn.y = aT2;     // B-head diag = own A-tail (s-2)
            #pragma unroll
            for (int k = 0; k < 4; ++k) {
                float2v wl = P[k];
                float2v s2 = pk_add(wl, dgn);       // left+diag, off the chain
                float2v a  = pk_mul(fsv[k], s2);
                float2v w  = pk_fma(fsv[k], uc, a); // packed fma chain
                dgn = wl; P[k] = w; uc = w;
            }
            aT2 = aT; aT = P[3].x;

            // pub: lanes in [max(0,(s-511)>>1), (s-1)>>1] — SALU mask
            // (verified vs (unsigned)(vj0-1)<512 at s=0,1,638,639)
            {
                int hi = (s - 1) >> 1;
                int lo = (s - 511) >> 1;
                lo = lo < 0 ? 0 : lo;
                unsigned long long mhi =
                    (hi < 0) ? 0ull
                             : ((hi >= 63) ? ~0ull : ((1ull << (hi + 1)) - 1ull));
                unsigned long long pmask =
                    (lo >= 64) ? 0ull : (mhi & (~0ull << lo));
                c7w = sel_f(pmask, P[3].y, c7w);
                c7E = sel_i(pmask, E, c7E);
            }
            pW = nW; pE = nEc;            // delay line — FROZEN, do not touch

            float zn = dpp_up1_f(zB);     // 2-substep/lane y delay line
            zB = zA;
            zA = lane0 ? f[q] : zn;
        }

        // per-blk renorm: B-tail -> ~[1,2); rescale (P,E) and the published
        // (c7w,c7E) together — implied u invariant, so snapshots stay exact.
        int ebits = (int)((__float_as_uint(P[3].y) >> 23) & 255u);
        int dsh = 127 - ebits;
        dsh = dsh > 126 ? 126 : (dsh < -126 ? -126 : dsh);
        float sf = exp2i(dsh);
        E += dsh;
        float2v sf2; sf2.x = sf; sf2.y = sf;
        #pragma unroll
        for (int k = 0; k < 4; ++k) P[k] = pk_mul(P[k], sf2);
        aT *= sf; aT2 *= sf;
        c7w *= sf; c7E += dsh;
    }

    float dtwv = 0.0f;
    if (lane == 63) {
        float u = (float)c7E - __builtin_amdgcn_logf(c7w);  // v_log = log2
        dtwv = fabsf(u) * (1.0f / KSC);                     // |R(511,511)|
    }

    // ---- init-free cross-block finalize (flag protocol; verified R12/R15/R17) ----
    float* slot = ws + 8 * b;
    if (lane == 63) slot[3] = dtwv;
    if (lane == 0) { slot[0] = sab; slot[1] = ssq; slot[2] = corr; }
    __syncthreads();
    __threadfence();
    if (lane == 0) atomicExch((int*)(slot + 4), MAGICF);   // release-publish

    if (b == NB - 1) {
        float m = 0.f, s = 0.f, p = 0.f, d = 0.f;
        if (lane < NB) {
            int* fl = (int*)(ws + 8 * lane + 4);
            while (atomicAdd(fl, 0) != MAGICF) { }         // acquire-spin
            __threadfence();
            float* sl = ws + 8 * lane;
            m = atomicAdd(&sl[0], 0.0f);
            s = atomicAdd(&sl[1], 0.0f);
            p = atomicAdd(&sl[2], 0.0f);
            d = atomicAdd(&sl[3], 0.0f);
        }
        #pragma unroll
        for (int mm = 1; mm < 64; mm <<= 1) {
            m += __shfl_xor(m, mm, 64);
            s += __shfl_xor(s, mm, 64);
            p += __shfl_xor(p, mm, 64);
            d += __shfl_xor(d, mm, 64);
        }
        if (lane == 0) {
            out[NB * TT + 0] = m;                         // mae_loss
            out[NB * TT + 1] = 1.0f - p * (1.0f / 32.0f); // pcc_loss
            out[NB * TT + 2] = d * (1.0f / 32.0f);        // dtw_loss
            out[NB * TT + 3] = sqrtf(s);                  // rmse_loss
        }
    }
}

extern "C" void kernel_launch(void* const* d_in, const int* in_sizes, int n_in,
                              void* d_out, int out_size, void* d_ws, size_t ws_size,
                              hipStream_t stream) {
    const float* pred_map = (const float*)d_in[0];
    const int*   lat_idx  = (const int*)d_in[1];
    const float* omega    = (const float*)d_in[2];
    const float* omni     = (const float*)d_in[3];
    float* out = (float*)d_out;
    float* ws  = (float*)d_ws;

    fused_kernel<<<NB, 64, 0, stream>>>(pred_map, lat_idx, omega, omni, out, ws);
}

// Round 6
// 137.535 us; speedup vs baseline: 1.0874x; 1.0874x over previous
//
#include <hip/hip_runtime.h>
#include <math.h>

#define TT 512
#define NB 32
#define NRSTEP 200
#define KSC 14.4269504f          // 10 * log2(e); u = KSC * R
#define MAGICF 0x5CA1AB1E

// Schraudolph fast 2^a for a in [-5, 0] (verified R8/R10/R12/R15/R17)
#define SCHR_SCALE (-KSC * 8388608.0f)
#define SCHR_OFF   1064986823.0f         // 127*2^23 - 366393

typedef float float2v __attribute__((ext_vector_type(2)));

// ---- forced VOP3P packed f32 ops (dual-issue FP32, gfx90a+/gfx950) ----
__device__ __forceinline__ float2v pk_add(float2v a, float2v b) {
    float2v d;
    asm("v_pk_add_f32 %0, %1, %2" : "=v"(d) : "v"(a), "v"(b));
    return d;
}
__device__ __forceinline__ float2v pk_mul(float2v a, float2v b) {
    float2v d;
    asm("v_pk_mul_f32 %0, %1, %2" : "=v"(d) : "v"(a), "v"(b));
    return d;
}
__device__ __forceinline__ float2v pk_fma(float2v a, float2v b, float2v c) {
    float2v d;
    asm("v_pk_fma_f32 %0, %1, %2, %3" : "=v"(d) : "v"(a), "v"(b), "v"(c));
    return d;
}
// d = c - a*b (packed fma, src0 negated via neg modifiers — exact) (R24)
__device__ __forceinline__ float2v pk_nfma(float2v a, float2v b, float2v c) {
    float2v d;
    asm("v_pk_fma_f32 %0, %1, %2, %3 neg_lo:[1,0,0] neg_hi:[1,0,0]"
        : "=v"(d) : "v"(a), "v"(b), "v"(c));
    return d;
}

// DPP wave_shr:1 — lane i <- lane i-1, lane 0 gets 0 (verified R5..R17)
__device__ __forceinline__ float dpp_up1_f(float x) {
    return __int_as_float(__builtin_amdgcn_update_dpp(
        0, __float_as_int(x), 0x138, 0xf, 0xf, false));
}
__device__ __forceinline__ int dpp_up1_i(int x) {
    return __builtin_amdgcn_update_dpp(0, x, 0x138, 0xf, 0xf, false);
}
__device__ __forceinline__ float rdlane_f(float v, int lane) {
    return __int_as_float(__builtin_amdgcn_readlane(__float_as_int(v), lane));
}
__device__ __forceinline__ float exp2i(int e) {   // 2^e, |e|<=126, no trans op
    return __int_as_float((e + 127) << 23);
}
// forced HW ldexp (bit-identical to ldexpf; avoids any ocml wrapper) (R24)
__device__ __forceinline__ float ldexp_f(float x, int e) {
    float d;
    asm("v_ldexp_f32 %0, %1, %2" : "=v"(d) : "v"(x), "v"(e));
    return d;
}

// ---------------- Fused kernel: gather + HUX + stats + soft-DTW + finalize ----
// one block (one wave) per batch b; lane owns rows t = lane*8 .. lane*8+7
// DP: R15/R17-proven MONOLITHIC w-domain 2-group packed sweep, exact
// per-substep exponent tracking.
//
// *** DP LOOP DATAFLOW IS FROZEN. ***
// Failed restructurings (outputs 0-2 pass, dtw=inf): R13/R14/R16 loop splits;
// R20/R21 wdA-carry (bit-identical on paper, fails on HW — CONVICTED).
// Perf-convicted: R23 SALU-mask selects (correct but +6 µs — cross-pipe
// SALU->VALU dependency stalls the 1-wave serial loop; keep selects on the
// VALU pipe: v_add/v_cmp/vcc/v_cndmask).
// Do NOT add loop-carried values, do NOT replace the pW/pE delay line,
// do NOT split the 80-blk loop, do NOT move selects to SALU.
//
// R18: hot packed math forced to v_pk_* via inline asm; y-pipeline carries
// NEGATED y so the D-term needs no modifiers (bit-identical).
// R19: HUX forced to v_pk_*; wrap-rotate via one ds_bpermute; int4 lat_idx.
// R22: HUX max(v,1) dropped — v provably stays in [300,700] (convex updates,
//      kappa<=0.55), proven safe by R20/R21 outputs 0-2 passing.
// R24: (1) HUX Newton neg-fold: 2-a*g as single pk_nfma (bit-identical);
//      (2) ldexpf -> forced v_ldexp_f32 (bit-identical);
//      (3) fsv reassociation: S(x+z)^2+O = fma(z^2,S, fma(z, 2Sx, Sx^2+O)),
//          z^2 shared across the 4 groups; 12 pk-ops -> 9 per substep.
//          Value-path only (weights perturbed <= 2^-22 rel; dtw thr 33.6).
__global__ __launch_bounds__(64, 1) void fused_kernel(
    const float* __restrict__ pred_map,  // [B,1,T,128]
    const int*   __restrict__ lat_idx,   // [B,T]
    const float* __restrict__ omega,     // [B]
    const float* __restrict__ omni,      // [B,T]
    float*       __restrict__ out,       // v_out at [0, B*T), scalars after
    float*       __restrict__ ws)
{
    const int b    = blockIdx.x;
    const int lane = threadIdx.x;
    const int t0   = lane * 8;
    const bool lane0 = (lane == 0);

    // ---- gather v_in ----
    float v[8];
    const int4* li4 = (const int4*)(lat_idx + b * TT + t0);
    const int4 liA = li4[0];
    const int4 liB = li4[1];
    int li[8] = {liA.x, liA.y, liA.z, liA.w, liB.x, liB.y, liB.z, liB.w};
    const float* pm = pred_map + (size_t)b * TT * 128 + (size_t)t0 * 128;
    #pragma unroll
    for (int k = 0; k < 8; ++k) v[k] = pm[k * 128 + li[k]];

    // ---- HUX-f: 200 upwind steps, packed: W[i] = {v[i], v[i+4]} (R17) ----
    const float c = (float)(673089.75 / (2.0 * M_PI / 512.0)) * omega[b];
    const float2v c2 = {c, c};
    const float2v kM1 = {-1.0f, -1.0f};
    const float2v kTwo = {2.0f, 2.0f};
    const int rot = ((lane + 1) & 63) << 2;   // bpermute byte addr: lane i+1 mod 64
    float2v W[4];
    W[0].x = v[0]; W[0].y = v[4];
    W[1].x = v[1]; W[1].y = v[5];
    W[2].x = v[2]; W[2].y = v[6];
    W[3].x = v[3]; W[3].y = v[7];
    #pragma unroll 2
    for (int it = 0; it < NRSTEP; ++it) {
        // wrap-rotate: lane i <- old v[0] of lane i+1 (lane 63 <- lane 0).
        float vn = __int_as_float(__builtin_amdgcn_ds_bpermute(
            rot, __float_as_int(W[0].x)));

        // r = fastrcp(W) : magic + 1 Newton, all packed.
        // max(v,1) dropped: identity on [300,700] (proven safe, R20/R21).
        float2v g0, g1, g2, g3;
        g0.x = __int_as_float(0x7EF311C3 - __float_as_int(W[0].x));
        g0.y = __int_as_float(0x7EF311C3 - __float_as_int(W[0].y));
        g1.x = __int_as_float(0x7EF311C3 - __float_as_int(W[1].x));
        g1.y = __int_as_float(0x7EF311C3 - __float_as_int(W[1].y));
        g2.x = __int_as_float(0x7EF311C3 - __float_as_int(W[2].x));
        g2.y = __int_as_float(0x7EF311C3 - __float_as_int(W[2].y));
        g3.x = __int_as_float(0x7EF311C3 - __float_as_int(W[3].x));
        g3.y = __int_as_float(0x7EF311C3 - __float_as_int(W[3].y));
        // r = g * (2 - W*g): Newton via single neg-fma (R24, bit-identical)
        float2v r0 = pk_mul(g0, pk_nfma(W[0], g0, kTwo));
        float2v r1 = pk_mul(g1, pk_nfma(W[1], g1, kTwo));
        float2v r2 = pk_mul(g2, pk_nfma(W[2], g2, kTwo));
        float2v r3 = pk_mul(g3, pk_nfma(W[3], g3, kTwo));

        float2v nb0 = W[1], nb1 = W[2], nb2 = W[3];
        float2v nb3; nb3.x = W[0].y; nb3.y = vn;

        // W += c2 * r * (nb - W)
        float2v d0 = pk_fma(W[0], kM1, nb0);
        float2v d1 = pk_fma(W[1], kM1, nb1);
        float2v d2 = pk_fma(W[2], kM1, nb2);
        float2v d3 = pk_fma(W[3], kM1, nb3);
        W[0] = pk_fma(pk_mul(r0, d0), c2, W[0]);
        W[1] = pk_fma(pk_mul(r1, d1), c2, W[1]);
        W[2] = pk_fma(pk_mul(r2, d2), c2, W[2]);
        W[3] = pk_fma(pk_mul(r3, d3), c2, W[3]);
    }
    v[0] = W[0].x; v[4] = W[0].y;
    v[1] = W[1].x; v[5] = W[1].y;
    v[2] = W[2].x; v[6] = W[2].y;
    v[3] = W[3].x; v[7] = W[3].y;

    // ---- write v_out ----
    float4* o4 = (float4*)(out + b * TT + t0);
    o4[0] = make_float4(v[0], v[1], v[2], v[3]);
    o4[1] = make_float4(v[4], v[5], v[6], v[7]);

    // ---- scaled series + per-b stats ----
    float x[8], y8[8], y8n[8];
    const float* om = omni + b * TT + t0;
    float sx = 0.f, syy0 = 0.f;
    #pragma unroll
    for (int k = 0; k < 8; ++k) {
        x[k]   = (om[k] - 200.0f) * 1e-3f;   // omni_scaled (rows)
        y8[k]  = (v[k] - 200.0f) * 1e-3f;    // v_out_scaled (cols)
        y8n[k] = -y8[k];                     // negated for the DP y-pipeline
        sx += x[k];
        syy0 += y8[k];
    }
    #pragma unroll
    for (int m = 1; m < 64; m <<= 1) {
        sx   += __shfl_xor(sx, m, 64);
        syy0 += __shfl_xor(syy0, m, 64);
    }
    const float mx = sx * (1.0f / 512.0f);
    const float my = syy0 * (1.0f / 512.0f);

    float sab = 0.f, ssq = 0.f, snum = 0.f, sxx = 0.f, spp = 0.f;
    #pragma unroll
    for (int k = 0; k < 8; ++k) {
        float d = y8[k] - x[k];
        sab += fabsf(d);
        ssq += d * d;
        float pc = y8[k] - my;
        float tc = x[k] - mx;
        snum += pc * tc;
        sxx  += tc * tc;
        spp  += pc * pc;
    }
    #pragma unroll
    for (int m = 1; m < 64; m <<= 1) {
        sab  += __shfl_xor(sab,  m, 64);
        ssq  += __shfl_xor(ssq,  m, 64);
        snum += __shfl_xor(snum, m, 64);
        sxx  += __shfl_xor(sxx,  m, 64);
        spp  += __shfl_xor(spp,  m, 64);
    }
    const float corr = snum / (sqrtf(spp) * sqrtf(sxx));

    // ---- soft-DTW, w-domain, 2-group packed, exact per-substep scales ----
    // (monolithic 80-blk loop — proven; z pipeline carries NEGATED y)
    float2v x2[4];
    #pragma unroll
    for (int i = 0; i < 4; ++i) { x2[i].x = x[i]; x2[i].y = x[i + 4]; }
    const float2v kS2 = {SCHR_SCALE, SCHR_SCALE};
    const float2v kO2 = {SCHR_OFF, SCHR_OFF};
    // R24 fsv constants: xB = 2*S*x, xA = S*x^2 + O (per lane, per group)
    const float2v k2S2 = {2.0f * SCHR_SCALE, 2.0f * SCHR_SCALE};
    float2v xA[4], xB[4];
    #pragma unroll
    for (int i = 0; i < 4; ++i) {
        xB[i] = pk_mul(x2[i], k2S2);
        xA[i] = pk_fma(pk_mul(x2[i], x2[i]), kS2, kO2);
    }

    float2v P[4];
    #pragma unroll
    for (int k = 0; k < 4; ++k) P[k] = (float2v){0.0f, 0.0f};
    int   E = 0;
    float c7w = 0.0f; int c7E = 0;    // published boundary (B-tail, row 8l+7)
    float aT = 0.0f, aT2 = 0.0f;      // A-tail (row 8l+3) delay line -> B-chain
    float pW = 0.0f;  int pE = 0;     // lane l-1 B-tail, two substeps back
    int   vj0 = -2 * lane;            // A-group col for upcoming substep
    const float adoptW = lane0 ? 1.0f : 0.0f;  // diag at adopt: origin / BIG

    // y pipeline (NEGATED): before substep s, zA(l) = -y[s-2l], zB(l) = -y[s-1-2l]
    float zA = lane0 ? y8n[0] : 0.0f;
    float zB = 0.0f;

    #pragma unroll 1
    for (int blk = 0; blk < 80; ++blk) {
        const int us  = blk < 63 ? blk : 63;
        const int us1 = blk < 62 ? blk + 1 : 63;   // readlane idx must be <= 63
        float f[8];
        f[0] = rdlane_f(y8n[1], us);
        f[1] = rdlane_f(y8n[2], us);
        f[2] = rdlane_f(y8n[3], us);
        f[3] = rdlane_f(y8n[4], us);
        f[4] = rdlane_f(y8n[5], us);
        f[5] = rdlane_f(y8n[6], us);
        f[6] = rdlane_f(y8n[7], us);
        f[7] = rdlane_f(y8n[0], us1);

        #pragma unroll
        for (int q = 0; q < 8; ++q) {
            float nW  = dpp_up1_f(c7w);   // lane l-1 B-tail at col j0 (scale nEc)
            int   nEc = dpp_up1_i(c7E);

            // D-factors (Schraudolph), R24 reassociated:
            // h = S*(x+z)^2 + O = fma(z^2, S, fma(z, 2Sx, Sx^2+O)); z^2 shared
            float2v z2; z2.x = zA; z2.y = zB;
            float2v zz = pk_mul(z2, z2);
            float2v fsv[4];
            #pragma unroll
            for (int i = 0; i < 4; ++i) {
                float2v h1 = pk_fma(z2, xB[i], xA[i]);
                float2v h  = pk_fma(zz, kS2, h1);
                fsv[i].x = __int_as_float((int)h.x);
                fsv[i].y = __int_as_float((int)h.y);
            }

            const bool adopt = (vj0 == 0);
            E = adopt ? nEc : E;          // adopt neighbor scale exactly
            float wuA = ldexp_f(nW, E - nEc);   // up for A-head, our scale
            float wdA = ldexp_f(pW, E - pE);    // diag for A-head
            wdA = adopt ? adoptW : wdA;         // col -1 = BIG; lane0 origin

            float2v uc, dgn;
            uc.x  = wuA; uc.y  = aT;      // B-head up = own A-tail (s-1)
            dgn.x = wdA; dgn.y = aT2;     // B-head diag = own A-tail (s-2)
            #pragma unroll
            for (int k = 0; k < 4; ++k) {
                float2v wl = P[k];
                float2v s  = pk_add(wl, dgn);       // left+diag, off the chain
                float2v a  = pk_mul(fsv[k], s);
                float2v w  = pk_fma(fsv[k], uc, a); // packed fma chain
                dgn = wl; P[k] = w; uc = w;
            }
            aT2 = aT; aT = P[3].x;

            const bool pub = ((unsigned)(vj0 - 1) < 512u);  // B col valid
            c7w = pub ? P[3].y : c7w;
            c7E = pub ? E : c7E;
            pW = nW; pE = nEc;            // delay line — FROZEN, do not touch

            float zn = dpp_up1_f(zB);     // 2-substep/lane y delay line
            zB = zA;
            zA = lane0 ? f[q] : zn;
            ++vj0;
        }

        // per-blk renorm: B-tail -> ~[1,2); rescale (P,E) and the published
        // (c7w,c7E) together — implied u invariant, so snapshots stay exact.
        int ebits = (int)((__float_as_uint(P[3].y) >> 23) & 255u);
        int dsh = 127 - ebits;
        dsh = dsh > 126 ? 126 : (dsh < -126 ? -126 : dsh);
        float sf = exp2i(dsh);
        E += dsh;
        float2v sf2; sf2.x = sf; sf2.y = sf;
        #pragma unroll
        for (int k = 0; k < 4; ++k) P[k] = pk_mul(P[k], sf2);
        aT *= sf; aT2 *= sf;
        c7w *= sf; c7E += dsh;
    }

    float dtwv = 0.0f;
    if (lane == 63) {
        float u = (float)c7E - __builtin_amdgcn_logf(c7w);  // v_log = log2
        dtwv = fabsf(u) * (1.0f / KSC);                     // |R(511,511)|
    }

    // ---- init-free cross-block finalize (flag protocol; verified R12/R15/R17) ----
    float* slot = ws + 8 * b;
    if (lane == 63) slot[3] = dtwv;
    if (lane == 0) { slot[0] = sab; slot[1] = ssq; slot[2] = corr; }
    __syncthreads();
    __threadfence();
    if (lane == 0) atomicExch((int*)(slot + 4), MAGICF);   // release-publish

    if (b == NB - 1) {
        float m = 0.f, s = 0.f, p = 0.f, d = 0.f;
        if (lane < NB) {
            int* fl = (int*)(ws + 8 * lane + 4);
            while (atomicAdd(fl, 0) != MAGICF) { }         // acquire-spin
            __threadfence();
            float* sl = ws + 8 * lane;
            m = atomicAdd(&sl[0], 0.0f);
            s = atomicAdd(&sl[1], 0.0f);
            p = atomicAdd(&sl[2], 0.0f);
            d = atomicAdd(&sl[3], 0.0f);
        }
        #pragma unroll
        for (int mm = 1; mm < 64; mm <<= 1) {
            m += __shfl_xor(m, mm, 64);
            s += __shfl_xor(s, mm, 64);
            p += __shfl_xor(p, mm, 64);
            d += __shfl_xor(d, mm, 64);
        }
        if (lane == 0) {
            out[NB * TT + 0] = m;                         // mae_loss
            out[NB * TT + 1] = 1.0f - p * (1.0f / 32.0f); // pcc_loss
            out[NB * TT + 2] = d * (1.0f / 32.0f);        // dtw_loss
            out[NB * TT + 3] = sqrtf(s);                  // rmse_loss
        }
    }
}

extern "C" void kernel_launch(void* const* d_in, const int* in_sizes, int n_in,
                              void* d_out, int out_size, void* d_ws, size_t ws_size,
                              hipStream_t stream) {
    const float* pred_map = (const float*)d_in[0];
    const int*   lat_idx  = (const int*)d_in[1];
    const float* omega    = (const float*)d_in[2];
    const float* omni     = (const float*)d_in[3];
    float* out = (float*)d_out;
    float* ws  = (float*)d_ws;

    fused_kernel<<<NB, 64, 0, stream>>>(pred_map, lat_idx, omega, omni, out, ws);
}

// Round 7
// 135.932 us; speedup vs baseline: 1.1002x; 1.0118x over previous
//
#include <hip/hip_runtime.h>
#include <math.h>

#define TT 512
#define NB 32
#define NRSTEP 200
#define KSC 14.4269504f          // 10 * log2(e); u = KSC * R
#define MAGICF 0x5CA1AB1E

// Schraudolph fast 2^a for a in [-5, 0] (verified R8/R10/R12/R15/R17)
#define SCHR_SCALE (-KSC * 8388608.0f)
#define SCHR_OFF   1064986823.0f         // 127*2^23 - 366393

typedef float float2v __attribute__((ext_vector_type(2)));

// ---- forced VOP3P packed f32 ops (dual-issue FP32, gfx90a+/gfx950) ----
__device__ __forceinline__ float2v pk_add(float2v a, float2v b) {
    float2v d;
    asm("v_pk_add_f32 %0, %1, %2" : "=v"(d) : "v"(a), "v"(b));
    return d;
}
__device__ __forceinline__ float2v pk_mul(float2v a, float2v b) {
    float2v d;
    asm("v_pk_mul_f32 %0, %1, %2" : "=v"(d) : "v"(a), "v"(b));
    return d;
}
__device__ __forceinline__ float2v pk_fma(float2v a, float2v b, float2v c) {
    float2v d;
    asm("v_pk_fma_f32 %0, %1, %2, %3" : "=v"(d) : "v"(a), "v"(b), "v"(c));
    return d;
}
// d = c - a*b (packed fma, src0 negated via neg modifiers — exact) (R24)
__device__ __forceinline__ float2v pk_nfma(float2v a, float2v b, float2v c) {
    float2v d;
    asm("v_pk_fma_f32 %0, %1, %2, %3 neg_lo:[1,0,0] neg_hi:[1,0,0]"
        : "=v"(d) : "v"(a), "v"(b), "v"(c));
    return d;
}

// DPP wave_shr:1 — lane i <- lane i-1, lane 0 gets 0 (verified R5..R17)
__device__ __forceinline__ float dpp_up1_f(float x) {
    return __int_as_float(__builtin_amdgcn_update_dpp(
        0, __float_as_int(x), 0x138, 0xf, 0xf, false));
}
__device__ __forceinline__ int dpp_up1_i(int x) {
    return __builtin_amdgcn_update_dpp(0, x, 0x138, 0xf, 0xf, false);
}
// DPP wave_shl:1 — lane i <- lane i+1, lane 63 gets 0 (HW-verified R13..R17)
__device__ __forceinline__ float dpp_dn1_f(float x) {
    return __int_as_float(__builtin_amdgcn_update_dpp(
        0, __float_as_int(x), 0x130, 0xf, 0xf, false));
}
__device__ __forceinline__ float rdlane_f(float v, int lane) {
    return __int_as_float(__builtin_amdgcn_readlane(__float_as_int(v), lane));
}
__device__ __forceinline__ float exp2i(int e) {   // 2^e, |e|<=126, no trans op
    return __int_as_float((e + 127) << 23);
}
// forced HW ldexp (bit-identical to ldexpf; avoids any ocml wrapper) (R24)
__device__ __forceinline__ float ldexp_f(float x, int e) {
    float d;
    asm("v_ldexp_f32 %0, %1, %2" : "=v"(d) : "v"(x), "v"(e));
    return d;
}

// ---------------- Fused kernel: gather + HUX + stats + soft-DTW + finalize ----
// one block (one wave) per batch b; lane owns rows t = lane*8 .. lane*8+7
// DP: R15/R17-proven MONOLITHIC w-domain 2-group packed sweep, exact
// per-substep exponent tracking.
//
// *** DP LOOP DATAFLOW IS FROZEN. ***
// Failed restructurings (outputs 0-2 pass, dtw=inf): R13/R14/R16 loop splits;
// R20/R21 wdA-carry (bit-identical on paper, fails on HW — CONVICTED).
// Perf-convicted: R23 SALU-mask selects (correct but +6 µs — cross-pipe
// SALU->VALU dependency stalls the 1-wave serial loop; keep selects on the
// VALU pipe: v_add/v_cmp/vcc/v_cndmask).
// Do NOT add loop-carried values, do NOT replace the pW/pE delay line,
// do NOT split the 80-blk loop, do NOT move selects to SALU.
//
// R18: hot packed math forced to v_pk_* via inline asm; y-pipeline carries
// NEGATED y so the D-term needs no modifiers (bit-identical).
// R19: HUX forced to v_pk_*; int4 lat_idx.
// R22: HUX max(v,1) dropped — v provably stays in [300,700] (convex updates,
//      kappa<=0.55), proven safe by R20/R21 outputs 0-2 passing.
// R24: HUX Newton neg-fold (pk_nfma, bit-identical); ldexpf -> v_ldexp_f32
//      (bit-identical); fsv reassociation z^2 shared (12->9 pk-ops/substep).
// R25: HUX wrap-rotate reverted ds_bpermute -> readlane+DPP-shl+cndmask
//      (R18-proven, bit-identical). Theory: per-iter lgkmcnt wait on the
//      serial 1-wave loop cost ~2-3 µs (masked in the R19 bundle); the
//      3-VALU form keeps the rotate on the already-paid-for VALU pipe.
__global__ __launch_bounds__(64, 1) void fused_kernel(
    const float* __restrict__ pred_map,  // [B,1,T,128]
    const int*   __restrict__ lat_idx,   // [B,T]
    const float* __restrict__ omega,     // [B]
    const float* __restrict__ omni,      // [B,T]
    float*       __restrict__ out,       // v_out at [0, B*T), scalars after
    float*       __restrict__ ws)
{
    const int b    = blockIdx.x;
    const int lane = threadIdx.x;
    const int t0   = lane * 8;
    const bool lane0 = (lane == 0);
    const bool lane63 = (lane == 63);    // hoisted mask for the HUX rotate

    // ---- gather v_in ----
    float v[8];
    const int4* li4 = (const int4*)(lat_idx + b * TT + t0);
    const int4 liA = li4[0];
    const int4 liB = li4[1];
    int li[8] = {liA.x, liA.y, liA.z, liA.w, liB.x, liB.y, liB.z, liB.w};
    const float* pm = pred_map + (size_t)b * TT * 128 + (size_t)t0 * 128;
    #pragma unroll
    for (int k = 0; k < 8; ++k) v[k] = pm[k * 128 + li[k]];

    // ---- HUX-f: 200 upwind steps, packed: W[i] = {v[i], v[i+4]} (R17) ----
    const float c = (float)(673089.75 / (2.0 * M_PI / 512.0)) * omega[b];
    const float2v c2 = {c, c};
    const float2v kM1 = {-1.0f, -1.0f};
    const float2v kTwo = {2.0f, 2.0f};
    float2v W[4];
    W[0].x = v[0]; W[0].y = v[4];
    W[1].x = v[1]; W[1].y = v[5];
    W[2].x = v[2]; W[2].y = v[6];
    W[3].x = v[3]; W[3].y = v[7];
    #pragma unroll 2
    for (int it = 0; it < NRSTEP; ++it) {
        // wrap-rotate: lane i <- old v[0] of lane i+1 (lane 63 <- lane 0).
        // R25: VALU-only form (readlane + DPP wave_shl + cndmask) — no
        // lgkmcnt wait on the serial loop. Bit-identical to the bpermute.
        float rd0 = rdlane_f(W[0].x, 0);     // old v[0] of lane 0 (wrap source)
        float vn  = dpp_dn1_f(W[0].x);       // old v[t0+8] (lane i <- i+1)
        vn = lane63 ? rd0 : vn;              // wrap 512 -> 0

        // r = fastrcp(W) : magic + 1 Newton, all packed.
        // max(v,1) dropped: identity on [300,700] (proven safe, R20/R21).
        float2v g0, g1, g2, g3;
        g0.x = __int_as_float(0x7EF311C3 - __float_as_int(W[0].x));
        g0.y = __int_as_float(0x7EF311C3 - __float_as_int(W[0].y));
        g1.x = __int_as_float(0x7EF311C3 - __float_as_int(W[1].x));
        g1.y = __int_as_float(0x7EF311C3 - __float_as_int(W[1].y));
        g2.x = __int_as_float(0x7EF311C3 - __float_as_int(W[2].x));
        g2.y = __int_as_float(0x7EF311C3 - __float_as_int(W[2].y));
        g3.x = __int_as_float(0x7EF311C3 - __float_as_int(W[3].x));
        g3.y = __int_as_float(0x7EF311C3 - __float_as_int(W[3].y));
        // r = g * (2 - W*g): Newton via single neg-fma (R24, bit-identical)
        float2v r0 = pk_mul(g0, pk_nfma(W[0], g0, kTwo));
        float2v r1 = pk_mul(g1, pk_nfma(W[1], g1, kTwo));
        float2v r2 = pk_mul(g2, pk_nfma(W[2], g2, kTwo));
        float2v r3 = pk_mul(g3, pk_nfma(W[3], g3, kTwo));

        float2v nb0 = W[1], nb1 = W[2], nb2 = W[3];
        float2v nb3; nb3.x = W[0].y; nb3.y = vn;

        // W += c2 * r * (nb - W)
        float2v d0 = pk_fma(W[0], kM1, nb0);
        float2v d1 = pk_fma(W[1], kM1, nb1);
        float2v d2 = pk_fma(W[2], kM1, nb2);
        float2v d3 = pk_fma(W[3], kM1, nb3);
        W[0] = pk_fma(pk_mul(r0, d0), c2, W[0]);
        W[1] = pk_fma(pk_mul(r1, d1), c2, W[1]);
        W[2] = pk_fma(pk_mul(r2, d2), c2, W[2]);
        W[3] = pk_fma(pk_mul(r3, d3), c2, W[3]);
    }
    v[0] = W[0].x; v[4] = W[0].y;
    v[1] = W[1].x; v[5] = W[1].y;
    v[2] = W[2].x; v[6] = W[2].y;
    v[3] = W[3].x; v[7] = W[3].y;

    // ---- write v_out ----
    float4* o4 = (float4*)(out + b * TT + t0);
    o4[0] = make_float4(v[0], v[1], v[2], v[3]);
    o4[1] = make_float4(v[4], v[5], v[6], v[7]);

    // ---- scaled series + per-b stats ----
    float x[8], y8[8], y8n[8];
    const float* om = omni + b * TT + t0;
    float sx = 0.f, syy0 = 0.f;
    #pragma unroll
    for (int k = 0; k < 8; ++k) {
        x[k]   = (om[k] - 200.0f) * 1e-3f;   // omni_scaled (rows)
        y8[k]  = (v[k] - 200.0f) * 1e-3f;    // v_out_scaled (cols)
        y8n[k] = -y8[k];                     // negated for the DP y-pipeline
        sx += x[k];
        syy0 += y8[k];
    }
    #pragma unroll
    for (int m = 1; m < 64; m <<= 1) {
        sx   += __shfl_xor(sx, m, 64);
        syy0 += __shfl_xor(syy0, m, 64);
    }
    const float mx = sx * (1.0f / 512.0f);
    const float my = syy0 * (1.0f / 512.0f);

    float sab = 0.f, ssq = 0.f, snum = 0.f, sxx = 0.f, spp = 0.f;
    #pragma unroll
    for (int k = 0; k < 8; ++k) {
        float d = y8[k] - x[k];
        sab += fabsf(d);
        ssq += d * d;
        float pc = y8[k] - my;
        float tc = x[k] - mx;
        snum += pc * tc;
        sxx  += tc * tc;
        spp  += pc * pc;
    }
    #pragma unroll
    for (int m = 1; m < 64; m <<= 1) {
        sab  += __shfl_xor(sab,  m, 64);
        ssq  += __shfl_xor(ssq,  m, 64);
        snum += __shfl_xor(snum, m, 64);
        sxx  += __shfl_xor(sxx,  m, 64);
        spp  += __shfl_xor(spp,  m, 64);
    }
    const float corr = snum / (sqrtf(spp) * sqrtf(sxx));

    // ---- soft-DTW, w-domain, 2-group packed, exact per-substep scales ----
    // (monolithic 80-blk loop — proven; z pipeline carries NEGATED y)
    float2v x2[4];
    #pragma unroll
    for (int i = 0; i < 4; ++i) { x2[i].x = x[i]; x2[i].y = x[i + 4]; }
    const float2v kS2 = {SCHR_SCALE, SCHR_SCALE};
    const float2v kO2 = {SCHR_OFF, SCHR_OFF};
    // R24 fsv constants: xB = 2*S*x, xA = S*x^2 + O (per lane, per group)
    const float2v k2S2 = {2.0f * SCHR_SCALE, 2.0f * SCHR_SCALE};
    float2v xA[4], xB[4];
    #pragma unroll
    for (int i = 0; i < 4; ++i) {
        xB[i] = pk_mul(x2[i], k2S2);
        xA[i] = pk_fma(pk_mul(x2[i], x2[i]), kS2, kO2);
    }

    float2v P[4];
    #pragma unroll
    for (int k = 0; k < 4; ++k) P[k] = (float2v){0.0f, 0.0f};
    int   E = 0;
    float c7w = 0.0f; int c7E = 0;    // published boundary (B-tail, row 8l+7)
    float aT = 0.0f, aT2 = 0.0f;      // A-tail (row 8l+3) delay line -> B-chain
    float pW = 0.0f;  int pE = 0;     // lane l-1 B-tail, two substeps back
    int   vj0 = -2 * lane;            // A-group col for upcoming substep
    const float adoptW = lane0 ? 1.0f : 0.0f;  // diag at adopt: origin / BIG

    // y pipeline (NEGATED): before substep s, zA(l) = -y[s-2l], zB(l) = -y[s-1-2l]
    float zA = lane0 ? y8n[0] : 0.0f;
    float zB = 0.0f;

    #pragma unroll 1
    for (int blk = 0; blk < 80; ++blk) {
        const int us  = blk < 63 ? blk : 63;
        const int us1 = blk < 62 ? blk + 1 : 63;   // readlane idx must be <= 63
        float f[8];
        f[0] = rdlane_f(y8n[1], us);
        f[1] = rdlane_f(y8n[2], us);
        f[2] = rdlane_f(y8n[3], us);
        f[3] = rdlane_f(y8n[4], us);
        f[4] = rdlane_f(y8n[5], us);
        f[5] = rdlane_f(y8n[6], us);
        f[6] = rdlane_f(y8n[7], us);
        f[7] = rdlane_f(y8n[0], us1);

        #pragma unroll
        for (int q = 0; q < 8; ++q) {
            float nW  = dpp_up1_f(c7w);   // lane l-1 B-tail at col j0 (scale nEc)
            int   nEc = dpp_up1_i(c7E);

            // D-factors (Schraudolph), R24 reassociated:
            // h = S*(x+z)^2 + O = fma(z^2, S, fma(z, 2Sx, Sx^2+O)); z^2 shared
            float2v z2; z2.x = zA; z2.y = zB;
            float2v zz = pk_mul(z2, z2);
            float2v fsv[4];
            #pragma unroll
            for (int i = 0; i < 4; ++i) {
                float2v h1 = pk_fma(z2, xB[i], xA[i]);
                float2v h  = pk_fma(zz, kS2, h1);
                fsv[i].x = __int_as_float((int)h.x);
                fsv[i].y = __int_as_float((int)h.y);
            }

            const bool adopt = (vj0 == 0);
            E = adopt ? nEc : E;          // adopt neighbor scale exactly
            float wuA = ldexp_f(nW, E - nEc);   // up for A-head, our scale
            float wdA = ldexp_f(pW, E - pE);    // diag for A-head
            wdA = adopt ? adoptW : wdA;         // col -1 = BIG; lane0 origin

            float2v uc, dgn;
            uc.x  = wuA; uc.y  = aT;      // B-head up = own A-tail (s-1)
            dgn.x = wdA; dgn.y = aT2;     // B-head diag = own A-tail (s-2)
            #pragma unroll
            for (int k = 0; k < 4; ++k) {
                float2v wl = P[k];
                float2v s  = pk_add(wl, dgn);       // left+diag, off the chain
                float2v a  = pk_mul(fsv[k], s);
                float2v w  = pk_fma(fsv[k], uc, a); // packed fma chain
                dgn = wl; P[k] = w; uc = w;
            }
            aT2 = aT; aT = P[3].x;

            const bool pub = ((unsigned)(vj0 - 1) < 512u);  // B col valid
            c7w = pub ? P[3].y : c7w;
            c7E = pub ? E : c7E;
            pW = nW; pE = nEc;            // delay line — FROZEN, do not touch

            float zn = dpp_up1_f(zB);     // 2-substep/lane y delay line
            zB = zA;
            zA = lane0 ? f[q] : zn;
            ++vj0;
        }

        // per-blk renorm: B-tail -> ~[1,2); rescale (P,E) and the published
        // (c7w,c7E) together — implied u invariant, so snapshots stay exact.
        int ebits = (int)((__float_as_uint(P[3].y) >> 23) & 255u);
        int dsh = 127 - ebits;
        dsh = dsh > 126 ? 126 : (dsh < -126 ? -126 : dsh);
        float sf = exp2i(dsh);
        E += dsh;
        float2v sf2; sf2.x = sf; sf2.y = sf;
        #pragma unroll
        for (int k = 0; k < 4; ++k) P[k] = pk_mul(P[k], sf2);
        aT *= sf; aT2 *= sf;
        c7w *= sf; c7E += dsh;
    }

    float dtwv = 0.0f;
    if (lane == 63) {
        float u = (float)c7E - __builtin_amdgcn_logf(c7w);  // v_log = log2
        dtwv = fabsf(u) * (1.0f / KSC);                     // |R(511,511)|
    }

    // ---- init-free cross-block finalize (flag protocol; verified R12/R15/R17) ----
    float* slot = ws + 8 * b;
    if (lane == 63) slot[3] = dtwv;
    if (lane == 0) { slot[0] = sab; slot[1] = ssq; slot[2] = corr; }
    __syncthreads();
    __threadfence();
    if (lane == 0) atomicExch((int*)(slot + 4), MAGICF);   // release-publish

    if (b == NB - 1) {
        float m = 0.f, s = 0.f, p = 0.f, d = 0.f;
        if (lane < NB) {
            int* fl = (int*)(ws + 8 * lane + 4);
            while (atomicAdd(fl, 0) != MAGICF) { }         // acquire-spin
            __threadfence();
            float* sl = ws + 8 * lane;
            m = atomicAdd(&sl[0], 0.0f);
            s = atomicAdd(&sl[1], 0.0f);
            p = atomicAdd(&sl[2], 0.0f);
            d = atomicAdd(&sl[3], 0.0f);
        }
        #pragma unroll
        for (int mm = 1; mm < 64; mm <<= 1) {
            m += __shfl_xor(m, mm, 64);
            s += __shfl_xor(s, mm, 64);
            p += __shfl_xor(p, mm, 64);
            d += __shfl_xor(d, mm, 64);
        }
        if (lane == 0) {
            out[NB * TT + 0] = m;                         // mae_loss
            out[NB * TT + 1] = 1.0f - p * (1.0f / 32.0f); // pcc_loss
            out[NB * TT + 2] = d * (1.0f / 32.0f);        // dtw_loss
            out[NB * TT + 3] = sqrtf(s);                  // rmse_loss
        }
    }
}

extern "C" void kernel_launch(void* const* d_in, const int* in_sizes, int n_in,
                              void* d_out, int out_size, void* d_ws, size_t ws_size,
                              hipStream_t stream) {
    const float* pred_map = (const float*)d_in[0];
    const int*   lat_idx  = (const int*)d_in[1];
    const float* omega    = (const float*)d_in[2];
    const float* omni     = (const float*)d_in[3];
    float* out = (float*)d_out;
    float* ws  = (float*)d_ws;

    fused_kernel<<<NB, 64, 0, stream>>>(pred_map, lat_idx, omega, omni, out, ws);
}

// Round 9
// 135.652 us; speedup vs baseline: 1.1025x; 1.0021x over previous
//
#include <hip/hip_runtime.h>
#include <math.h>

#define TT 512
#define NB 32
#define NRSTEP 200
#define KSC 14.4269504f          // 10 * log2(e); u = KSC * R
#define MAGICF 0x5CA1AB1E

// Schraudolph fast 2^a for a in [-5, 0] (verified R8/R10/R12/R15/R17)
#define SCHR_SCALE (-KSC * 8388608.0f)
#define SCHR_OFF   1064986823.0f         // 127*2^23 - 366393

typedef float float2v __attribute__((ext_vector_type(2)));

// ---- forced VOP3P packed f32 ops ----
// R25 calibration: v_pk_*_f32 issues in 4 cyc wave64 on CDNA4 (no f32
// throughput gain vs 2 scalars @2cyc) — value is code density + regfile
// ports. Cost model: pk = 4 cyc, scalar VALU = 2 cyc.
__device__ __forceinline__ float2v pk_add(float2v a, float2v b) {
    float2v d;
    asm("v_pk_add_f32 %0, %1, %2" : "=v"(d) : "v"(a), "v"(b));
    return d;
}
__device__ __forceinline__ float2v pk_mul(float2v a, float2v b) {
    float2v d;
    asm("v_pk_mul_f32 %0, %1, %2" : "=v"(d) : "v"(a), "v"(b));
    return d;
}
__device__ __forceinline__ float2v pk_fma(float2v a, float2v b, float2v c) {
    float2v d;
    asm("v_pk_fma_f32 %0, %1, %2, %3" : "=v"(d) : "v"(a), "v"(b), "v"(c));
    return d;
}
// d = c - a*b (packed fma, src0 negated via neg modifiers — exact) (R24)
__device__ __forceinline__ float2v pk_nfma(float2v a, float2v b, float2v c) {
    float2v d;
    asm("v_pk_fma_f32 %0, %1, %2, %3 neg_lo:[1,0,0] neg_hi:[1,0,0]"
        : "=v"(d) : "v"(a), "v"(b), "v"(c));
    return d;
}

// DPP wave_shr:1 — lane i <- lane i-1, lane 0 gets 0 (verified R5..R17)
__device__ __forceinline__ float dpp_up1_f(float x) {
    return __int_as_float(__builtin_amdgcn_update_dpp(
        0, __float_as_int(x), 0x138, 0xf, 0xf, false));
}
__device__ __forceinline__ int dpp_up1_i(int x) {
    return __builtin_amdgcn_update_dpp(0, x, 0x138, 0xf, 0xf, false);
}
// DPP wave_shl:1 — lane i <- lane i+1, lane 63 gets 0 (HW-verified R13..R17)
__device__ __forceinline__ float dpp_dn1_f(float x) {
    return __int_as_float(__builtin_amdgcn_update_dpp(
        0, __float_as_int(x), 0x130, 0xf, 0xf, false));
}
__device__ __forceinline__ float rdlane_f(float v, int lane) {
    return __int_as_float(__builtin_amdgcn_readlane(__float_as_int(v), lane));
}
__device__ __forceinline__ float exp2i(int e) {   // 2^e, |e|<=126, no trans op
    return __int_as_float((e + 127) << 23);
}
// forced HW ldexp (bit-identical to ldexpf; avoids any ocml wrapper) (R24)
__device__ __forceinline__ float ldexp_f(float x, int e) {
    float d;
    asm("v_ldexp_f32 %0, %1, %2" : "=v"(d) : "v"(x), "v"(e));
    return d;
}

// ---------------- Fused kernel: gather + HUX + stats + soft-DTW + finalize ----
// one block (one wave) per batch b; lane owns rows t = lane*8 .. lane*8+7
// DP: R15/R17-proven MONOLITHIC w-domain 2-group packed sweep, exact
// per-substep exponent tracking.
//
// *** DP LOOP DATAFLOW IS FROZEN. ***
// Failed restructurings (outputs 0-2 pass, dtw=inf): R13/R14/R16 loop splits;
// R20/R21 wdA-carry (bit-identical on paper, fails on HW — CONVICTED).
// Perf-convicted: R23 SALU-mask selects (correct but +6 µs — cross-pipe
// SALU->VALU dependency stalls the 1-wave serial loop; keep selects on the
// VALU pipe: v_add/v_cmp/vcc/v_cndmask).
// Do NOT add loop-carried values, do NOT replace the pW/pE delay line,
// do NOT split the 80-blk loop, do NOT move selects to SALU.
//
// R18: hot packed math forced to v_pk_* via inline asm; y-pipeline carries
// NEGATED y so the D-term needs no modifiers (bit-identical).
// R19: HUX forced to v_pk_*; int4 lat_idx.
// R22: HUX max(v,1) dropped — v provably stays in [300,700] (convex updates,
//      kappa<=0.55), proven safe by R20/R21 outputs 0-2 passing.
// R24: HUX Newton neg-fold (pk_nfma); ldexpf -> v_ldexp_f32; fsv
//      reassociation z^2 shared (12->9 pk-ops/substep).
// R25: HUX wrap-rotate: ds_bpermute -> readlane+DPP-shl+cndmask (VALU pipe).
// R26/R27: (1) HUX wrap via v_writelane inline asm (no builtin on this
//          toolchain — R26's compile error): readlane SGPR feeds
//          v_writelane_b32 lane 63 directly; drops the cndmask. Bit-identical.
//          (2) DP blk-loop unroll 2 (isolated; correctness-proven green in
//          R23's bundle) — overlaps renorm with next blk's readlanes/fsv.
//          NOT a split: identical body, no phase-dependent code.
__global__ __launch_bounds__(64, 1) void fused_kernel(
    const float* __restrict__ pred_map,  // [B,1,T,128]
    const int*   __restrict__ lat_idx,   // [B,T]
    const float* __restrict__ omega,     // [B]
    const float* __restrict__ omni,      // [B,T]
    float*       __restrict__ out,       // v_out at [0, B*T), scalars after
    float*       __restrict__ ws)
{
    const int b    = blockIdx.x;
    const int lane = threadIdx.x;
    const int t0   = lane * 8;
    const bool lane0 = (lane == 0);

    // ---- gather v_in ----
    float v[8];
    const int4* li4 = (const int4*)(lat_idx + b * TT + t0);
    const int4 liA = li4[0];
    const int4 liB = li4[1];
    int li[8] = {liA.x, liA.y, liA.z, liA.w, liB.x, liB.y, liB.z, liB.w};
    const float* pm = pred_map + (size_t)b * TT * 128 + (size_t)t0 * 128;
    #pragma unroll
    for (int k = 0; k < 8; ++k) v[k] = pm[k * 128 + li[k]];

    // ---- HUX-f: 200 upwind steps, packed: W[i] = {v[i], v[i+4]} (R17) ----
    const float c = (float)(673089.75 / (2.0 * M_PI / 512.0)) * omega[b];
    const float2v c2 = {c, c};
    const float2v kM1 = {-1.0f, -1.0f};
    const float2v kTwo = {2.0f, 2.0f};
    float2v W[4];
    W[0].x = v[0]; W[0].y = v[4];
    W[1].x = v[1]; W[1].y = v[5];
    W[2].x = v[2]; W[2].y = v[6];
    W[3].x = v[3]; W[3].y = v[7];
    #pragma unroll 2
    for (int it = 0; it < NRSTEP; ++it) {
        // wrap-rotate: lane i <- old v[0] of lane i+1 (lane 63 <- lane 0).
        // R27: readlane -> SGPR -> v_writelane_b32 into lane 63 of the DPP
        // shift (inline asm; exec-ignoring). One instr fewer than cndmask;
        // bit-identical.
        int rd0 = __builtin_amdgcn_readlane(__float_as_int(W[0].x), 0);
        int vni = __builtin_amdgcn_update_dpp(
            0, __float_as_int(W[0].x), 0x130, 0xf, 0xf, false);
        asm("v_writelane_b32 %0, %1, 63" : "+v"(vni) : "s"(rd0));
        float vn = __int_as_float(vni);

        // r = fastrcp(W) : magic + 1 Newton, all packed.
        // max(v,1) dropped: identity on [300,700] (proven safe, R20/R21).
        float2v g0, g1, g2, g3;
        g0.x = __int_as_float(0x7EF311C3 - __float_as_int(W[0].x));
        g0.y = __int_as_float(0x7EF311C3 - __float_as_int(W[0].y));
        g1.x = __int_as_float(0x7EF311C3 - __float_as_int(W[1].x));
        g1.y = __int_as_float(0x7EF311C3 - __float_as_int(W[1].y));
        g2.x = __int_as_float(0x7EF311C3 - __float_as_int(W[2].x));
        g2.y = __int_as_float(0x7EF311C3 - __float_as_int(W[2].y));
        g3.x = __int_as_float(0x7EF311C3 - __float_as_int(W[3].x));
        g3.y = __int_as_float(0x7EF311C3 - __float_as_int(W[3].y));
        // r = g * (2 - W*g): Newton via single neg-fma (R24, bit-identical)
        float2v r0 = pk_mul(g0, pk_nfma(W[0], g0, kTwo));
        float2v r1 = pk_mul(g1, pk_nfma(W[1], g1, kTwo));
        float2v r2 = pk_mul(g2, pk_nfma(W[2], g2, kTwo));
        float2v r3 = pk_mul(g3, pk_nfma(W[3], g3, kTwo));

        float2v nb0 = W[1], nb1 = W[2], nb2 = W[3];
        float2v nb3; nb3.x = W[0].y; nb3.y = vn;

        // W += c2 * r * (nb - W)
        float2v d0 = pk_fma(W[0], kM1, nb0);
        float2v d1 = pk_fma(W[1], kM1, nb1);
        float2v d2 = pk_fma(W[2], kM1, nb2);
        float2v d3 = pk_fma(W[3], kM1, nb3);
        W[0] = pk_fma(pk_mul(r0, d0), c2, W[0]);
        W[1] = pk_fma(pk_mul(r1, d1), c2, W[1]);
        W[2] = pk_fma(pk_mul(r2, d2), c2, W[2]);
        W[3] = pk_fma(pk_mul(r3, d3), c2, W[3]);
    }
    v[0] = W[0].x; v[4] = W[0].y;
    v[1] = W[1].x; v[5] = W[1].y;
    v[2] = W[2].x; v[6] = W[2].y;
    v[3] = W[3].x; v[7] = W[3].y;

    // ---- write v_out ----
    float4* o4 = (float4*)(out + b * TT + t0);
    o4[0] = make_float4(v[0], v[1], v[2], v[3]);
    o4[1] = make_float4(v[4], v[5], v[6], v[7]);

    // ---- scaled series + per-b stats ----
    float x[8], y8[8], y8n[8];
    const float* om = omni + b * TT + t0;
    float sx = 0.f, syy0 = 0.f;
    #pragma unroll
    for (int k = 0; k < 8; ++k) {
        x[k]   = (om[k] - 200.0f) * 1e-3f;   // omni_scaled (rows)
        y8[k]  = (v[k] - 200.0f) * 1e-3f;    // v_out_scaled (cols)
        y8n[k] = -y8[k];                     // negated for the DP y-pipeline
        sx += x[k];
        syy0 += y8[k];
    }
    #pragma unroll
    for (int m = 1; m < 64; m <<= 1) {
        sx   += __shfl_xor(sx, m, 64);
        syy0 += __shfl_xor(syy0, m, 64);
    }
    const float mx = sx * (1.0f / 512.0f);
    const float my = syy0 * (1.0f / 512.0f);

    float sab = 0.f, ssq = 0.f, snum = 0.f, sxx = 0.f, spp = 0.f;
    #pragma unroll
    for (int k = 0; k < 8; ++k) {
        float d = y8[k] - x[k];
        sab += fabsf(d);
        ssq += d * d;
        float pc = y8[k] - my;
        float tc = x[k] - mx;
        snum += pc * tc;
        sxx  += tc * tc;
        spp  += pc * pc;
    }
    #pragma unroll
    for (int m = 1; m < 64; m <<= 1) {
        sab  += __shfl_xor(sab,  m, 64);
        ssq  += __shfl_xor(ssq,  m, 64);
        snum += __shfl_xor(snum, m, 64);
        sxx  += __shfl_xor(sxx,  m, 64);
        spp  += __shfl_xor(spp,  m, 64);
    }
    const float corr = snum / (sqrtf(spp) * sqrtf(sxx));

    // ---- soft-DTW, w-domain, 2-group packed, exact per-substep scales ----
    // (monolithic 80-blk loop — proven; z pipeline carries NEGATED y)
    float2v x2[4];
    #pragma unroll
    for (int i = 0; i < 4; ++i) { x2[i].x = x[i]; x2[i].y = x[i + 4]; }
    const float2v kS2 = {SCHR_SCALE, SCHR_SCALE};
    const float2v kO2 = {SCHR_OFF, SCHR_OFF};
    // R24 fsv constants: xB = 2*S*x, xA = S*x^2 + O (per lane, per group)
    const float2v k2S2 = {2.0f * SCHR_SCALE, 2.0f * SCHR_SCALE};
    float2v xA[4], xB[4];
    #pragma unroll
    for (int i = 0; i < 4; ++i) {
        xB[i] = pk_mul(x2[i], k2S2);
        xA[i] = pk_fma(pk_mul(x2[i], x2[i]), kS2, kO2);
    }

    float2v P[4];
    #pragma unroll
    for (int k = 0; k < 4; ++k) P[k] = (float2v){0.0f, 0.0f};
    int   E = 0;
    float c7w = 0.0f; int c7E = 0;    // published boundary (B-tail, row 8l+7)
    float aT = 0.0f, aT2 = 0.0f;      // A-tail (row 8l+3) delay line -> B-chain
    float pW = 0.0f;  int pE = 0;     // lane l-1 B-tail, two substeps back
    int   vj0 = -2 * lane;            // A-group col for upcoming substep
    const float adoptW = lane0 ? 1.0f : 0.0f;  // diag at adopt: origin / BIG

    // y pipeline (NEGATED): before substep s, zA(l) = -y[s-2l], zB(l) = -y[s-1-2l]
    float zA = lane0 ? y8n[0] : 0.0f;
    float zB = 0.0f;

    #pragma unroll 2
    for (int blk = 0; blk < 80; ++blk) {
        const int us  = blk < 63 ? blk : 63;
        const int us1 = blk < 62 ? blk + 1 : 63;   // readlane idx must be <= 63
        float f[8];
        f[0] = rdlane_f(y8n[1], us);
        f[1] = rdlane_f(y8n[2], us);
        f[2] = rdlane_f(y8n[3], us);
        f[3] = rdlane_f(y8n[4], us);
        f[4] = rdlane_f(y8n[5], us);
        f[5] = rdlane_f(y8n[6], us);
        f[6] = rdlane_f(y8n[7], us);
        f[7] = rdlane_f(y8n[0], us1);

        #pragma unroll
        for (int q = 0; q < 8; ++q) {
            float nW  = dpp_up1_f(c7w);   // lane l-1 B-tail at col j0 (scale nEc)
            int   nEc = dpp_up1_i(c7E);

            // D-factors (Schraudolph), R24 reassociated:
            // h = S*(x+z)^2 + O = fma(z^2, S, fma(z, 2Sx, Sx^2+O)); z^2 shared
            float2v z2; z2.x = zA; z2.y = zB;
            float2v zz = pk_mul(z2, z2);
            float2v fsv[4];
            #pragma unroll
            for (int i = 0; i < 4; ++i) {
                float2v h1 = pk_fma(z2, xB[i], xA[i]);
                float2v h  = pk_fma(zz, kS2, h1);
                fsv[i].x = __int_as_float((int)h.x);
                fsv[i].y = __int_as_float((int)h.y);
            }

            const bool adopt = (vj0 == 0);
            E = adopt ? nEc : E;          // adopt neighbor scale exactly
            float wuA = ldexp_f(nW, E - nEc);   // up for A-head, our scale
            float wdA = ldexp_f(pW, E - pE);    // diag for A-head
            wdA = adopt ? adoptW : wdA;         // col -1 = BIG; lane0 origin

            float2v uc, dgn;
            uc.x  = wuA; uc.y  = aT;      // B-head up = own A-tail (s-1)
            dgn.x = wdA; dgn.y = aT2;     // B-head diag = own A-tail (s-2)
            #pragma unroll
            for (int k = 0; k < 4; ++k) {
                float2v wl = P[k];
                float2v s  = pk_add(wl, dgn);       // left+diag, off the chain
                float2v a  = pk_mul(fsv[k], s);
                float2v w  = pk_fma(fsv[k], uc, a); // packed fma chain
                dgn = wl; P[k] = w; uc = w;
            }
            aT2 = aT; aT = P[3].x;

            const bool pub = ((unsigned)(vj0 - 1) < 512u);  // B col valid
            c7w = pub ? P[3].y : c7w;
            c7E = pub ? E : c7E;
            pW = nW; pE = nEc;            // delay line — FROZEN, do not touch

            float zn = dpp_up1_f(zB);     // 2-substep/lane y delay line
            zB = zA;
            zA = lane0 ? f[q] : zn;
            ++vj0;
        }

        // per-blk renorm: B-tail -> ~[1,2); rescale (P,E) and the published
        // (c7w,c7E) together — implied u invariant, so snapshots stay exact.
        int ebits = (int)((__float_as_uint(P[3].y) >> 23) & 255u);
        int dsh = 127 - ebits;
        dsh = dsh > 126 ? 126 : (dsh < -126 ? -126 : dsh);
        float sf = exp2i(dsh);
        E += dsh;
        float2v sf2; sf2.x = sf; sf2.y = sf;
        #pragma unroll
        for (int k = 0; k < 4; ++k) P[k] = pk_mul(P[k], sf2);
        aT *= sf; aT2 *= sf;
        c7w *= sf; c7E += dsh;
    }

    float dtwv = 0.0f;
    if (lane == 63) {
        float u = (float)c7E - __builtin_amdgcn_logf(c7w);  // v_log = log2
        dtwv = fabsf(u) * (1.0f / KSC);                     // |R(511,511)|
    }

    // ---- init-free cross-block finalize (flag protocol; verified R12/R15/R17) ----
    float* slot = ws + 8 * b;
    if (lane == 63) slot[3] = dtwv;
    if (lane == 0) { slot[0] = sab; slot[1] = ssq; slot[2] = corr; }
    __syncthreads();
    __threadfence();
    if (lane == 0) atomicExch((int*)(slot + 4), MAGICF);   // release-publish

    if (b == NB - 1) {
        float m = 0.f, s = 0.f, p = 0.f, d = 0.f;
        if (lane < NB) {
            int* fl = (int*)(ws + 8 * lane + 4);
            while (atomicAdd(fl, 0) != MAGICF) { }         // acquire-spin
            __threadfence();
            float* sl = ws + 8 * lane;
            m = atomicAdd(&sl[0], 0.0f);
            s = atomicAdd(&sl[1], 0.0f);
            p = atomicAdd(&sl[2], 0.0f);
            d = atomicAdd(&sl[3], 0.0f);
        }
        #pragma unroll
        for (int mm = 1; mm < 64; mm <<= 1) {
            m += __shfl_xor(m, mm, 64);
            s += __shfl_xor(s, mm, 64);
            p += __shfl_xor(p, mm, 64);
            d += __shfl_xor(d, mm, 64);
        }
        if (lane == 0) {
            out[NB * TT + 0] = m;                         // mae_loss
            out[NB * TT + 1] = 1.0f - p * (1.0f / 32.0f); // pcc_loss
            out[NB * TT + 2] = d * (1.0f / 32.0f);        // dtw_loss
            out[NB * TT + 3] = sqrtf(s);                  // rmse_loss
        }
    }
}

extern "C" void kernel_launch(void* const* d_in, const int* in_sizes, int n_in,
                              void* d_out, int out_size, void* d_ws, size_t ws_size,
                              hipStream_t stream) {
    const float* pred_map = (const float*)d_in[0];
    const int*   lat_idx  = (const int*)d_in[1];
    const float* omega    = (const float*)d_in[2];
    const float* omni     = (const float*)d_in[3];
    float* out = (float*)d_out;
    float* ws  = (float*)d_ws;

    fused_kernel<<<NB, 64, 0, stream>>>(pred_map, lat_idx, omega, omni, out, ws);
}

// Round 10
// 134.110 us; speedup vs baseline: 1.1152x; 1.0115x over previous
//
#include <hip/hip_runtime.h>
#include <math.h>

#define TT 512
#define NB 32
#define NRSTEP 200
#define KSC 14.4269504f          // 10 * log2(e); u = KSC * R
#define MAGICF 0x5CA1AB1E

// Schraudolph fast 2^a for a in [-5, 0] (verified R8/R10/R12/R15/R17)
#define SCHR_SCALE (-KSC * 8388608.0f)
#define SCHR_OFF   1064986823.0f         // 127*2^23 - 366393

typedef float float2v __attribute__((ext_vector_type(2)));

// ---- forced VOP3P packed f32 ops ----
// R25 calibration: v_pk_*_f32 issues in 4 cyc wave64 on CDNA4 (no f32
// throughput gain vs 2 scalars @2cyc) — value is code density + regfile
// ports. Cost model: pk = 4 cyc, scalar VALU = 2 cyc.
__device__ __forceinline__ float2v pk_add(float2v a, float2v b) {
    float2v d;
    asm("v_pk_add_f32 %0, %1, %2" : "=v"(d) : "v"(a), "v"(b));
    return d;
}
__device__ __forceinline__ float2v pk_mul(float2v a, float2v b) {
    float2v d;
    asm("v_pk_mul_f32 %0, %1, %2" : "=v"(d) : "v"(a), "v"(b));
    return d;
}
__device__ __forceinline__ float2v pk_fma(float2v a, float2v b, float2v c) {
    float2v d;
    asm("v_pk_fma_f32 %0, %1, %2, %3" : "=v"(d) : "v"(a), "v"(b), "v"(c));
    return d;
}
// d = c - a*b (packed fma, src0 negated via neg modifiers — exact) (R24)
__device__ __forceinline__ float2v pk_nfma(float2v a, float2v b, float2v c) {
    float2v d;
    asm("v_pk_fma_f32 %0, %1, %2, %3 neg_lo:[1,0,0] neg_hi:[1,0,0]"
        : "=v"(d) : "v"(a), "v"(b), "v"(c));
    return d;
}

// DPP wave_shr:1 — lane i <- lane i-1, lane 0 gets 0 (verified R5..R17)
__device__ __forceinline__ float dpp_up1_f(float x) {
    return __int_as_float(__builtin_amdgcn_update_dpp(
        0, __float_as_int(x), 0x138, 0xf, 0xf, false));
}
__device__ __forceinline__ int dpp_up1_i(int x) {
    return __builtin_amdgcn_update_dpp(0, x, 0x138, 0xf, 0xf, false);
}
// DPP wave_shl:1 — lane i <- lane i+1, lane 63 gets 0 (HW-verified R13..R17)
__device__ __forceinline__ float dpp_dn1_f(float x) {
    return __int_as_float(__builtin_amdgcn_update_dpp(
        0, __float_as_int(x), 0x130, 0xf, 0xf, false));
}
__device__ __forceinline__ float rdlane_f(float v, int lane) {
    return __int_as_float(__builtin_amdgcn_readlane(__float_as_int(v), lane));
}
__device__ __forceinline__ float exp2i(int e) {   // 2^e, |e|<=126, no trans op
    return __int_as_float((e + 127) << 23);
}
// forced HW ldexp (bit-identical to ldexpf; avoids any ocml wrapper) (R24)
__device__ __forceinline__ float ldexp_f(float x, int e) {
    float d;
    asm("v_ldexp_f32 %0, %1, %2" : "=v"(d) : "v"(x), "v"(e));
    return d;
}

// ---------------- Fused kernel: gather + HUX + stats + soft-DTW + finalize ----
// one block (one wave) per batch b; lane owns rows t = lane*8 .. lane*8+7
// DP: R15/R17-proven MONOLITHIC w-domain 2-group packed sweep, exact
// per-substep exponent tracking.
//
// *** DP LOOP DATAFLOW IS FROZEN. ***
// Failed restructurings (outputs 0-2 pass, dtw=inf): R13/R14/R16 loop splits;
// R20/R21 wdA-carry (bit-identical on paper, fails on HW — CONVICTED).
// Perf-convicted: R23 SALU-mask selects (correct but +6 µs — cross-pipe
// SALU->VALU dependency stalls the 1-wave serial loop; keep selects on the
// VALU pipe: v_add/v_cmp/vcc/v_cndmask).
// Do NOT add loop-carried values, do NOT replace the pW/pE delay line,
// do NOT split the 80-blk loop, do NOT move selects to SALU.
//
// R18: hot packed math forced to v_pk_* via inline asm; y-pipeline carries
// NEGATED y so the D-term needs no modifiers (bit-identical).
// R19: HUX forced to v_pk_*; int4 lat_idx.
// R22: HUX max(v,1) dropped — v provably stays in [300,700] (convex updates,
//      kappa<=0.55), proven safe by R20/R21 outputs 0-2 passing.
// R24: HUX Newton neg-fold (pk_nfma); ldexpf -> v_ldexp_f32; fsv
//      reassociation z^2 shared (12->9 pk-ops/substep).
// R25: HUX wrap-rotate: ds_bpermute -> readlane+DPP-shl (VALU pipe).
// R27: HUX wrap via v_writelane_b32 inline asm; DP blk-loop unroll 2.
//      Result: 89.3 -> 80.0 µs. The blk-backedge seam (renorm serialized
//      against next blk's readlanes) was ~7 µs — scheduling-window widening
//      is the dominant remaining lever.
// R28: widen further — DP blk-loop unroll 4, HUX unroll 4. Pure pragmas,
//      identical body, zero dataflow contact (R23 precedent: both green).
__global__ __launch_bounds__(64, 1) void fused_kernel(
    const float* __restrict__ pred_map,  // [B,1,T,128]
    const int*   __restrict__ lat_idx,   // [B,T]
    const float* __restrict__ omega,     // [B]
    const float* __restrict__ omni,      // [B,T]
    float*       __restrict__ out,       // v_out at [0, B*T), scalars after
    float*       __restrict__ ws)
{
    const int b    = blockIdx.x;
    const int lane = threadIdx.x;
    const int t0   = lane * 8;
    const bool lane0 = (lane == 0);

    // ---- gather v_in ----
    float v[8];
    const int4* li4 = (const int4*)(lat_idx + b * TT + t0);
    const int4 liA = li4[0];
    const int4 liB = li4[1];
    int li[8] = {liA.x, liA.y, liA.z, liA.w, liB.x, liB.y, liB.z, liB.w};
    const float* pm = pred_map + (size_t)b * TT * 128 + (size_t)t0 * 128;
    #pragma unroll
    for (int k = 0; k < 8; ++k) v[k] = pm[k * 128 + li[k]];

    // ---- HUX-f: 200 upwind steps, packed: W[i] = {v[i], v[i+4]} (R17) ----
    const float c = (float)(673089.75 / (2.0 * M_PI / 512.0)) * omega[b];
    const float2v c2 = {c, c};
    const float2v kM1 = {-1.0f, -1.0f};
    const float2v kTwo = {2.0f, 2.0f};
    float2v W[4];
    W[0].x = v[0]; W[0].y = v[4];
    W[1].x = v[1]; W[1].y = v[5];
    W[2].x = v[2]; W[2].y = v[6];
    W[3].x = v[3]; W[3].y = v[7];
    #pragma unroll 4
    for (int it = 0; it < NRSTEP; ++it) {
        // wrap-rotate: lane i <- old v[0] of lane i+1 (lane 63 <- lane 0).
        // R27: readlane -> SGPR -> v_writelane_b32 into lane 63 of the DPP
        // shift (inline asm; exec-ignoring). Bit-identical.
        int rd0 = __builtin_amdgcn_readlane(__float_as_int(W[0].x), 0);
        int vni = __builtin_amdgcn_update_dpp(
            0, __float_as_int(W[0].x), 0x130, 0xf, 0xf, false);
        asm("v_writelane_b32 %0, %1, 63" : "+v"(vni) : "s"(rd0));
        float vn = __int_as_float(vni);

        // r = fastrcp(W) : magic + 1 Newton, all packed.
        // max(v,1) dropped: identity on [300,700] (proven safe, R20/R21).
        float2v g0, g1, g2, g3;
        g0.x = __int_as_float(0x7EF311C3 - __float_as_int(W[0].x));
        g0.y = __int_as_float(0x7EF311C3 - __float_as_int(W[0].y));
        g1.x = __int_as_float(0x7EF311C3 - __float_as_int(W[1].x));
        g1.y = __int_as_float(0x7EF311C3 - __float_as_int(W[1].y));
        g2.x = __int_as_float(0x7EF311C3 - __float_as_int(W[2].x));
        g2.y = __int_as_float(0x7EF311C3 - __float_as_int(W[2].y));
        g3.x = __int_as_float(0x7EF311C3 - __float_as_int(W[3].x));
        g3.y = __int_as_float(0x7EF311C3 - __float_as_int(W[3].y));
        // r = g * (2 - W*g): Newton via single neg-fma (R24, bit-identical)
        float2v r0 = pk_mul(g0, pk_nfma(W[0], g0, kTwo));
        float2v r1 = pk_mul(g1, pk_nfma(W[1], g1, kTwo));
        float2v r2 = pk_mul(g2, pk_nfma(W[2], g2, kTwo));
        float2v r3 = pk_mul(g3, pk_nfma(W[3], g3, kTwo));

        float2v nb0 = W[1], nb1 = W[2], nb2 = W[3];
        float2v nb3; nb3.x = W[0].y; nb3.y = vn;

        // W += c2 * r * (nb - W)
        float2v d0 = pk_fma(W[0], kM1, nb0);
        float2v d1 = pk_fma(W[1], kM1, nb1);
        float2v d2 = pk_fma(W[2], kM1, nb2);
        float2v d3 = pk_fma(W[3], kM1, nb3);
        W[0] = pk_fma(pk_mul(r0, d0), c2, W[0]);
        W[1] = pk_fma(pk_mul(r1, d1), c2, W[1]);
        W[2] = pk_fma(pk_mul(r2, d2), c2, W[2]);
        W[3] = pk_fma(pk_mul(r3, d3), c2, W[3]);
    }
    v[0] = W[0].x; v[4] = W[0].y;
    v[1] = W[1].x; v[5] = W[1].y;
    v[2] = W[2].x; v[6] = W[2].y;
    v[3] = W[3].x; v[7] = W[3].y;

    // ---- write v_out ----
    float4* o4 = (float4*)(out + b * TT + t0);
    o4[0] = make_float4(v[0], v[1], v[2], v[3]);
    o4[1] = make_float4(v[4], v[5], v[6], v[7]);

    // ---- scaled series + per-b stats ----
    float x[8], y8[8], y8n[8];
    const float* om = omni + b * TT + t0;
    float sx = 0.f, syy0 = 0.f;
    #pragma unroll
    for (int k = 0; k < 8; ++k) {
        x[k]   = (om[k] - 200.0f) * 1e-3f;   // omni_scaled (rows)
        y8[k]  = (v[k] - 200.0f) * 1e-3f;    // v_out_scaled (cols)
        y8n[k] = -y8[k];                     // negated for the DP y-pipeline
        sx += x[k];
        syy0 += y8[k];
    }
    #pragma unroll
    for (int m = 1; m < 64; m <<= 1) {
        sx   += __shfl_xor(sx, m, 64);
        syy0 += __shfl_xor(syy0, m, 64);
    }
    const float mx = sx * (1.0f / 512.0f);
    const float my = syy0 * (1.0f / 512.0f);

    float sab = 0.f, ssq = 0.f, snum = 0.f, sxx = 0.f, spp = 0.f;
    #pragma unroll
    for (int k = 0; k < 8; ++k) {
        float d = y8[k] - x[k];
        sab += fabsf(d);
        ssq += d * d;
        float pc = y8[k] - my;
        float tc = x[k] - mx;
        snum += pc * tc;
        sxx  += tc * tc;
        spp  += pc * pc;
    }
    #pragma unroll
    for (int m = 1; m < 64; m <<= 1) {
        sab  += __shfl_xor(sab,  m, 64);
        ssq  += __shfl_xor(ssq,  m, 64);
        snum += __shfl_xor(snum, m, 64);
        sxx  += __shfl_xor(sxx,  m, 64);
        spp  += __shfl_xor(spp,  m, 64);
    }
    const float corr = snum / (sqrtf(spp) * sqrtf(sxx));

    // ---- soft-DTW, w-domain, 2-group packed, exact per-substep scales ----
    // (monolithic 80-blk loop — proven; z pipeline carries NEGATED y)
    float2v x2[4];
    #pragma unroll
    for (int i = 0; i < 4; ++i) { x2[i].x = x[i]; x2[i].y = x[i + 4]; }
    const float2v kS2 = {SCHR_SCALE, SCHR_SCALE};
    const float2v kO2 = {SCHR_OFF, SCHR_OFF};
    // R24 fsv constants: xB = 2*S*x, xA = S*x^2 + O (per lane, per group)
    const float2v k2S2 = {2.0f * SCHR_SCALE, 2.0f * SCHR_SCALE};
    float2v xA[4], xB[4];
    #pragma unroll
    for (int i = 0; i < 4; ++i) {
        xB[i] = pk_mul(x2[i], k2S2);
        xA[i] = pk_fma(pk_mul(x2[i], x2[i]), kS2, kO2);
    }

    float2v P[4];
    #pragma unroll
    for (int k = 0; k < 4; ++k) P[k] = (float2v){0.0f, 0.0f};
    int   E = 0;
    float c7w = 0.0f; int c7E = 0;    // published boundary (B-tail, row 8l+7)
    float aT = 0.0f, aT2 = 0.0f;      // A-tail (row 8l+3) delay line -> B-chain
    float pW = 0.0f;  int pE = 0;     // lane l-1 B-tail, two substeps back
    int   vj0 = -2 * lane;            // A-group col for upcoming substep
    const float adoptW = lane0 ? 1.0f : 0.0f;  // diag at adopt: origin / BIG

    // y pipeline (NEGATED): before substep s, zA(l) = -y[s-2l], zB(l) = -y[s-1-2l]
    float zA = lane0 ? y8n[0] : 0.0f;
    float zB = 0.0f;

    #pragma unroll 4
    for (int blk = 0; blk < 80; ++blk) {
        const int us  = blk < 63 ? blk : 63;
        const int us1 = blk < 62 ? blk + 1 : 63;   // readlane idx must be <= 63
        float f[8];
        f[0] = rdlane_f(y8n[1], us);
        f[1] = rdlane_f(y8n[2], us);
        f[2] = rdlane_f(y8n[3], us);
        f[3] = rdlane_f(y8n[4], us);
        f[4] = rdlane_f(y8n[5], us);
        f[5] = rdlane_f(y8n[6], us);
        f[6] = rdlane_f(y8n[7], us);
        f[7] = rdlane_f(y8n[0], us1);

        #pragma unroll
        for (int q = 0; q < 8; ++q) {
            float nW  = dpp_up1_f(c7w);   // lane l-1 B-tail at col j0 (scale nEc)
            int   nEc = dpp_up1_i(c7E);

            // D-factors (Schraudolph), R24 reassociated:
            // h = S*(x+z)^2 + O = fma(z^2, S, fma(z, 2Sx, Sx^2+O)); z^2 shared
            float2v z2; z2.x = zA; z2.y = zB;
            float2v zz = pk_mul(z2, z2);
            float2v fsv[4];
            #pragma unroll
            for (int i = 0; i < 4; ++i) {
                float2v h1 = pk_fma(z2, xB[i], xA[i]);
                float2v h  = pk_fma(zz, kS2, h1);
                fsv[i].x = __int_as_float((int)h.x);
                fsv[i].y = __int_as_float((int)h.y);
            }

            const bool adopt = (vj0 == 0);
            E = adopt ? nEc : E;          // adopt neighbor scale exactly
            float wuA = ldexp_f(nW, E - nEc);   // up for A-head, our scale
            float wdA = ldexp_f(pW, E - pE);    // diag for A-head
            wdA = adopt ? adoptW : wdA;         // col -1 = BIG; lane0 origin

            float2v uc, dgn;
            uc.x  = wuA; uc.y  = aT;      // B-head up = own A-tail (s-1)
            dgn.x = wdA; dgn.y = aT2;     // B-head diag = own A-tail (s-2)
            #pragma unroll
            for (int k = 0; k < 4; ++k) {
                float2v wl = P[k];
                float2v s  = pk_add(wl, dgn);       // left+diag, off the chain
                float2v a  = pk_mul(fsv[k], s);
                float2v w  = pk_fma(fsv[k], uc, a); // packed fma chain
                dgn = wl; P[k] = w; uc = w;
            }
            aT2 = aT; aT = P[3].x;

            const bool pub = ((unsigned)(vj0 - 1) < 512u);  // B col valid
            c7w = pub ? P[3].y : c7w;
            c7E = pub ? E : c7E;
            pW = nW; pE = nEc;            // delay line — FROZEN, do not touch

            float zn = dpp_up1_f(zB);     // 2-substep/lane y delay line
            zB = zA;
            zA = lane0 ? f[q] : zn;
            ++vj0;
        }

        // per-blk renorm: B-tail -> ~[1,2); rescale (P,E) and the published
        // (c7w,c7E) together — implied u invariant, so snapshots stay exact.
        int ebits = (int)((__float_as_uint(P[3].y) >> 23) & 255u);
        int dsh = 127 - ebits;
        dsh = dsh > 126 ? 126 : (dsh < -126 ? -126 : dsh);
        float sf = exp2i(dsh);
        E += dsh;
        float2v sf2; sf2.x = sf; sf2.y = sf;
        #pragma unroll
        for (int k = 0; k < 4; ++k) P[k] = pk_mul(P[k], sf2);
        aT *= sf; aT2 *= sf;
        c7w *= sf; c7E += dsh;
    }

    float dtwv = 0.0f;
    if (lane == 63) {
        float u = (float)c7E - __builtin_amdgcn_logf(c7w);  // v_log = log2
        dtwv = fabsf(u) * (1.0f / KSC);                     // |R(511,511)|
    }

    // ---- init-free cross-block finalize (flag protocol; verified R12/R15/R17) ----
    float* slot = ws + 8 * b;
    if (lane == 63) slot[3] = dtwv;
    if (lane == 0) { slot[0] = sab; slot[1] = ssq; slot[2] = corr; }
    __syncthreads();
    __threadfence();
    if (lane == 0) atomicExch((int*)(slot + 4), MAGICF);   // release-publish

    if (b == NB - 1) {
        float m = 0.f, s = 0.f, p = 0.f, d = 0.f;
        if (lane < NB) {
            int* fl = (int*)(ws + 8 * lane + 4);
            while (atomicAdd(fl, 0) != MAGICF) { }         // acquire-spin
            __threadfence();
            float* sl = ws + 8 * lane;
            m = atomicAdd(&sl[0], 0.0f);
            s = atomicAdd(&sl[1], 0.0f);
            p = atomicAdd(&sl[2], 0.0f);
            d = atomicAdd(&sl[3], 0.0f);
        }
        #pragma unroll
        for (int mm = 1; mm < 64; mm <<= 1) {
            m += __shfl_xor(m, mm, 64);
            s += __shfl_xor(s, mm, 64);
            p += __shfl_xor(p, mm, 64);
            d += __shfl_xor(d, mm, 64);
        }
        if (lane == 0) {
            out[NB * TT + 0] = m;                         // mae_loss
            out[NB * TT + 1] = 1.0f - p * (1.0f / 32.0f); // pcc_loss
            out[NB * TT + 2] = d * (1.0f / 32.0f);        // dtw_loss
            out[NB * TT + 3] = sqrtf(s);                  // rmse_loss
        }
    }
}

extern "C" void kernel_launch(void* const* d_in, const int* in_sizes, int n_in,
                              void* d_out, int out_size, void* d_ws, size_t ws_size,
                              hipStream_t stream) {
    const float* pred_map = (const float*)d_in[0];
    const int*   lat_idx  = (const int*)d_in[1];
    const float* omega    = (const float*)d_in[2];
    const float* omni     = (const float*)d_in[3];
    float* out = (float*)d_out;
    float* ws  = (float*)d_ws;

    fused_kernel<<<NB, 64, 0, stream>>>(pred_map, lat_idx, omega, omni, out, ws);
}

// Round 11
// 133.739 us; speedup vs baseline: 1.1183x; 1.0028x over previous
//
#include <hip/hip_runtime.h>
#include <math.h>

#define TT 512
#define NB 32
#define NRSTEP 200
#define KSC 14.4269504f          // 10 * log2(e); u = KSC * R
#define MAGICF 0x5CA1AB1E

// Schraudolph fast 2^a for a in [-5, 0] (verified R8/R10/R12/R15/R17)
#define SCHR_SCALE (-KSC * 8388608.0f)
#define SCHR_OFF   1064986823.0f         // 127*2^23 - 366393

typedef float float2v __attribute__((ext_vector_type(2)));

// ---- forced VOP3P packed f32 ops ----
// R25 calibration: v_pk_*_f32 issues in 4 cyc wave64 on CDNA4 (no f32
// throughput gain vs 2 scalars @2cyc) — value is code density + regfile
// ports. Cost model: pk = 4 cyc, scalar VALU = 2 cyc.
__device__ __forceinline__ float2v pk_add(float2v a, float2v b) {
    float2v d;
    asm("v_pk_add_f32 %0, %1, %2" : "=v"(d) : "v"(a), "v"(b));
    return d;
}
__device__ __forceinline__ float2v pk_mul(float2v a, float2v b) {
    float2v d;
    asm("v_pk_mul_f32 %0, %1, %2" : "=v"(d) : "v"(a), "v"(b));
    return d;
}
__device__ __forceinline__ float2v pk_fma(float2v a, float2v b, float2v c) {
    float2v d;
    asm("v_pk_fma_f32 %0, %1, %2, %3" : "=v"(d) : "v"(a), "v"(b), "v"(c));
    return d;
}
// d = c - a*b (packed fma, src0 negated via neg modifiers — exact) (R24)
__device__ __forceinline__ float2v pk_nfma(float2v a, float2v b, float2v c) {
    float2v d;
    asm("v_pk_fma_f32 %0, %1, %2, %3 neg_lo:[1,0,0] neg_hi:[1,0,0]"
        : "=v"(d) : "v"(a), "v"(b), "v"(c));
    return d;
}

// DPP wave_shr:1 — lane i <- lane i-1, lane 0 gets 0 (verified R5..R17)
__device__ __forceinline__ float dpp_up1_f(float x) {
    return __int_as_float(__builtin_amdgcn_update_dpp(
        0, __float_as_int(x), 0x138, 0xf, 0xf, false));
}
__device__ __forceinline__ int dpp_up1_i(int x) {
    return __builtin_amdgcn_update_dpp(0, x, 0x138, 0xf, 0xf, false);
}
// DPP wave_shl:1 — lane i <- lane i+1, lane 63 gets 0 (HW-verified R13..R17)
__device__ __forceinline__ float dpp_dn1_f(float x) {
    return __int_as_float(__builtin_amdgcn_update_dpp(
        0, __float_as_int(x), 0x130, 0xf, 0xf, false));
}
__device__ __forceinline__ float rdlane_f(float v, int lane) {
    return __int_as_float(__builtin_amdgcn_readlane(__float_as_int(v), lane));
}
__device__ __forceinline__ float exp2i(int e) {   // 2^e, |e|<=126, no trans op
    return __int_as_float((e + 127) << 23);
}
// forced HW ldexp (bit-identical to ldexpf; avoids any ocml wrapper) (R24)
__device__ __forceinline__ float ldexp_f(float x, int e) {
    float d;
    asm("v_ldexp_f32 %0, %1, %2" : "=v"(d) : "v"(x), "v"(e));
    return d;
}

// ---------------- Fused kernel: gather + HUX + stats + soft-DTW + finalize ----
// one block (one wave) per batch b; lane owns rows t = lane*8 .. lane*8+7
// DP: R15/R17-proven MONOLITHIC w-domain 2-group packed sweep, exact
// per-substep exponent tracking.
//
// *** DP LOOP DATAFLOW IS FROZEN. ***
// Failed restructurings (outputs 0-2 pass, dtw=inf): R13/R14/R16 loop splits;
// R20/R21 wdA-carry (bit-identical on paper, fails on HW — CONVICTED).
// Perf-convicted: R23 SALU-mask selects (correct but +6 µs — cross-pipe
// SALU->VALU dependency stalls the 1-wave serial loop; keep selects on the
// VALU pipe: v_add/v_cmp/vcc/v_cndmask).
// Do NOT add loop-carried values, do NOT replace the pW/pE delay line,
// do NOT split the 80-blk loop, do NOT move selects to SALU.
//
// R18: hot packed math forced to v_pk_* via inline asm; y-pipeline carries
// NEGATED y so the D-term needs no modifiers (bit-identical).
// R19: HUX forced to v_pk_*; int4 lat_idx.
// R22: HUX max(v,1) dropped — v provably stays in [300,700] (convex updates,
//      kappa<=0.55), proven safe by R20/R21 outputs 0-2 passing.
// R24: HUX Newton neg-fold (pk_nfma); ldexpf -> v_ldexp_f32; fsv
//      reassociation z^2 shared (12->9 pk-ops/substep).
// R25: HUX wrap-rotate: ds_bpermute -> readlane+DPP-shl (VALU pipe).
// R27: HUX wrap via v_writelane_b32 inline asm; DP blk-loop unroll 2
//      (89.3 -> 80.0 µs: the blk-backedge seam was ~7 µs).
// R28: unroll 4 both loops (80.0 -> 78.2: seam lever saturating).
// R29: unroll 8 both loops — final window doubling. Pre-committed: if
//      Δ < 1.5 µs, the frozen-DP structural floor is reached (issue model:
//      DP ~35 µs + HUX ~8.5 + misc ~4 = ~47 µs issue; residual = carried
//      c7w->dpp->ldexp->fma-chain latency, untouchable without dataflow
//      changes that HW-fail).
__global__ __launch_bounds__(64, 1) void fused_kernel(
    const float* __restrict__ pred_map,  // [B,1,T,128]
    const int*   __restrict__ lat_idx,   // [B,T]
    const float* __restrict__ omega,     // [B]
    const float* __restrict__ omni,      // [B,T]
    float*       __restrict__ out,       // v_out at [0, B*T), scalars after
    float*       __restrict__ ws)
{
    const int b    = blockIdx.x;
    const int lane = threadIdx.x;
    const int t0   = lane * 8;
    const bool lane0 = (lane == 0);

    // ---- gather v_in ----
    float v[8];
    const int4* li4 = (const int4*)(lat_idx + b * TT + t0);
    const int4 liA = li4[0];
    const int4 liB = li4[1];
    int li[8] = {liA.x, liA.y, liA.z, liA.w, liB.x, liB.y, liB.z, liB.w};
    const float* pm = pred_map + (size_t)b * TT * 128 + (size_t)t0 * 128;
    #pragma unroll
    for (int k = 0; k < 8; ++k) v[k] = pm[k * 128 + li[k]];

    // ---- HUX-f: 200 upwind steps, packed: W[i] = {v[i], v[i+4]} (R17) ----
    const float c = (float)(673089.75 / (2.0 * M_PI / 512.0)) * omega[b];
    const float2v c2 = {c, c};
    const float2v kM1 = {-1.0f, -1.0f};
    const float2v kTwo = {2.0f, 2.0f};
    float2v W[4];
    W[0].x = v[0]; W[0].y = v[4];
    W[1].x = v[1]; W[1].y = v[5];
    W[2].x = v[2]; W[2].y = v[6];
    W[3].x = v[3]; W[3].y = v[7];
    #pragma unroll 8
    for (int it = 0; it < NRSTEP; ++it) {
        // wrap-rotate: lane i <- old v[0] of lane i+1 (lane 63 <- lane 0).
        // R27: readlane -> SGPR -> v_writelane_b32 into lane 63 of the DPP
        // shift (inline asm; exec-ignoring). Bit-identical.
        int rd0 = __builtin_amdgcn_readlane(__float_as_int(W[0].x), 0);
        int vni = __builtin_amdgcn_update_dpp(
            0, __float_as_int(W[0].x), 0x130, 0xf, 0xf, false);
        asm("v_writelane_b32 %0, %1, 63" : "+v"(vni) : "s"(rd0));
        float vn = __int_as_float(vni);

        // r = fastrcp(W) : magic + 1 Newton, all packed.
        // max(v,1) dropped: identity on [300,700] (proven safe, R20/R21).
        float2v g0, g1, g2, g3;
        g0.x = __int_as_float(0x7EF311C3 - __float_as_int(W[0].x));
        g0.y = __int_as_float(0x7EF311C3 - __float_as_int(W[0].y));
        g1.x = __int_as_float(0x7EF311C3 - __float_as_int(W[1].x));
        g1.y = __int_as_float(0x7EF311C3 - __float_as_int(W[1].y));
        g2.x = __int_as_float(0x7EF311C3 - __float_as_int(W[2].x));
        g2.y = __int_as_float(0x7EF311C3 - __float_as_int(W[2].y));
        g3.x = __int_as_float(0x7EF311C3 - __float_as_int(W[3].x));
        g3.y = __int_as_float(0x7EF311C3 - __float_as_int(W[3].y));
        // r = g * (2 - W*g): Newton via single neg-fma (R24, bit-identical)
        float2v r0 = pk_mul(g0, pk_nfma(W[0], g0, kTwo));
        float2v r1 = pk_mul(g1, pk_nfma(W[1], g1, kTwo));
        float2v r2 = pk_mul(g2, pk_nfma(W[2], g2, kTwo));
        float2v r3 = pk_mul(g3, pk_nfma(W[3], g3, kTwo));

        float2v nb0 = W[1], nb1 = W[2], nb2 = W[3];
        float2v nb3; nb3.x = W[0].y; nb3.y = vn;

        // W += c2 * r * (nb - W)
        float2v d0 = pk_fma(W[0], kM1, nb0);
        float2v d1 = pk_fma(W[1], kM1, nb1);
        float2v d2 = pk_fma(W[2], kM1, nb2);
        float2v d3 = pk_fma(W[3], kM1, nb3);
        W[0] = pk_fma(pk_mul(r0, d0), c2, W[0]);
        W[1] = pk_fma(pk_mul(r1, d1), c2, W[1]);
        W[2] = pk_fma(pk_mul(r2, d2), c2, W[2]);
        W[3] = pk_fma(pk_mul(r3, d3), c2, W[3]);
    }
    v[0] = W[0].x; v[4] = W[0].y;
    v[1] = W[1].x; v[5] = W[1].y;
    v[2] = W[2].x; v[6] = W[2].y;
    v[3] = W[3].x; v[7] = W[3].y;

    // ---- write v_out ----
    float4* o4 = (float4*)(out + b * TT + t0);
    o4[0] = make_float4(v[0], v[1], v[2], v[3]);
    o4[1] = make_float4(v[4], v[5], v[6], v[7]);

    // ---- scaled series + per-b stats ----
    float x[8], y8[8], y8n[8];
    const float* om = omni + b * TT + t0;
    float sx = 0.f, syy0 = 0.f;
    #pragma unroll
    for (int k = 0; k < 8; ++k) {
        x[k]   = (om[k] - 200.0f) * 1e-3f;   // omni_scaled (rows)
        y8[k]  = (v[k] - 200.0f) * 1e-3f;    // v_out_scaled (cols)
        y8n[k] = -y8[k];                     // negated for the DP y-pipeline
        sx += x[k];
        syy0 += y8[k];
    }
    #pragma unroll
    for (int m = 1; m < 64; m <<= 1) {
        sx   += __shfl_xor(sx, m, 64);
        syy0 += __shfl_xor(syy0, m, 64);
    }
    const float mx = sx * (1.0f / 512.0f);
    const float my = syy0 * (1.0f / 512.0f);

    float sab = 0.f, ssq = 0.f, snum = 0.f, sxx = 0.f, spp = 0.f;
    #pragma unroll
    for (int k = 0; k < 8; ++k) {
        float d = y8[k] - x[k];
        sab += fabsf(d);
        ssq += d * d;
        float pc = y8[k] - my;
        float tc = x[k] - mx;
        snum += pc * tc;
        sxx  += tc * tc;
        spp  += pc * pc;
    }
    #pragma unroll
    for (int m = 1; m < 64; m <<= 1) {
        sab  += __shfl_xor(sab,  m, 64);
        ssq  += __shfl_xor(ssq,  m, 64);
        snum += __shfl_xor(snum, m, 64);
        sxx  += __shfl_xor(sxx,  m, 64);
        spp  += __shfl_xor(spp,  m, 64);
    }
    const float corr = snum / (sqrtf(spp) * sqrtf(sxx));

    // ---- soft-DTW, w-domain, 2-group packed, exact per-substep scales ----
    // (monolithic 80-blk loop — proven; z pipeline carries NEGATED y)
    float2v x2[4];
    #pragma unroll
    for (int i = 0; i < 4; ++i) { x2[i].x = x[i]; x2[i].y = x[i + 4]; }
    const float2v kS2 = {SCHR_SCALE, SCHR_SCALE};
    const float2v kO2 = {SCHR_OFF, SCHR_OFF};
    // R24 fsv constants: xB = 2*S*x, xA = S*x^2 + O (per lane, per group)
    const float2v k2S2 = {2.0f * SCHR_SCALE, 2.0f * SCHR_SCALE};
    float2v xA[4], xB[4];
    #pragma unroll
    for (int i = 0; i < 4; ++i) {
        xB[i] = pk_mul(x2[i], k2S2);
        xA[i] = pk_fma(pk_mul(x2[i], x2[i]), kS2, kO2);
    }

    float2v P[4];
    #pragma unroll
    for (int k = 0; k < 4; ++k) P[k] = (float2v){0.0f, 0.0f};
    int   E = 0;
    float c7w = 0.0f; int c7E = 0;    // published boundary (B-tail, row 8l+7)
    float aT = 0.0f, aT2 = 0.0f;      // A-tail (row 8l+3) delay line -> B-chain
    float pW = 0.0f;  int pE = 0;     // lane l-1 B-tail, two substeps back
    int   vj0 = -2 * lane;            // A-group col for upcoming substep
    const float adoptW = lane0 ? 1.0f : 0.0f;  // diag at adopt: origin / BIG

    // y pipeline (NEGATED): before substep s, zA(l) = -y[s-2l], zB(l) = -y[s-1-2l]
    float zA = lane0 ? y8n[0] : 0.0f;
    float zB = 0.0f;

    #pragma unroll 8
    for (int blk = 0; blk < 80; ++blk) {
        const int us  = blk < 63 ? blk : 63;
        const int us1 = blk < 62 ? blk + 1 : 63;   // readlane idx must be <= 63
        float f[8];
        f[0] = rdlane_f(y8n[1], us);
        f[1] = rdlane_f(y8n[2], us);
        f[2] = rdlane_f(y8n[3], us);
        f[3] = rdlane_f(y8n[4], us);
        f[4] = rdlane_f(y8n[5], us);
        f[5] = rdlane_f(y8n[6], us);
        f[6] = rdlane_f(y8n[7], us);
        f[7] = rdlane_f(y8n[0], us1);

        #pragma unroll
        for (int q = 0; q < 8; ++q) {
            float nW  = dpp_up1_f(c7w);   // lane l-1 B-tail at col j0 (scale nEc)
            int   nEc = dpp_up1_i(c7E);

            // D-factors (Schraudolph), R24 reassociated:
            // h = S*(x+z)^2 + O = fma(z^2, S, fma(z, 2Sx, Sx^2+O)); z^2 shared
            float2v z2; z2.x = zA; z2.y = zB;
            float2v zz = pk_mul(z2, z2);
            float2v fsv[4];
            #pragma unroll
            for (int i = 0; i < 4; ++i) {
                float2v h1 = pk_fma(z2, xB[i], xA[i]);
                float2v h  = pk_fma(zz, kS2, h1);
                fsv[i].x = __int_as_float((int)h.x);
                fsv[i].y = __int_as_float((int)h.y);
            }

            const bool adopt = (vj0 == 0);
            E = adopt ? nEc : E;          // adopt neighbor scale exactly
            float wuA = ldexp_f(nW, E - nEc);   // up for A-head, our scale
            float wdA = ldexp_f(pW, E - pE);    // diag for A-head
            wdA = adopt ? adoptW : wdA;         // col -1 = BIG; lane0 origin

            float2v uc, dgn;
            uc.x  = wuA; uc.y  = aT;      // B-head up = own A-tail (s-1)
            dgn.x = wdA; dgn.y = aT2;     // B-head diag = own A-tail (s-2)
            #pragma unroll
            for (int k = 0; k < 4; ++k) {
                float2v wl = P[k];
                float2v s  = pk_add(wl, dgn);       // left+diag, off the chain
                float2v a  = pk_mul(fsv[k], s);
                float2v w  = pk_fma(fsv[k], uc, a); // packed fma chain
                dgn = wl; P[k] = w; uc = w;
            }
            aT2 = aT; aT = P[3].x;

            const bool pub = ((unsigned)(vj0 - 1) < 512u);  // B col valid
            c7w = pub ? P[3].y : c7w;
            c7E = pub ? E : c7E;
            pW = nW; pE = nEc;            // delay line — FROZEN, do not touch

            float zn = dpp_up1_f(zB);     // 2-substep/lane y delay line
            zB = zA;
            zA = lane0 ? f[q] : zn;
            ++vj0;
        }

        // per-blk renorm: B-tail -> ~[1,2); rescale (P,E) and the published
        // (c7w,c7E) together — implied u invariant, so snapshots stay exact.
        int ebits = (int)((__float_as_uint(P[3].y) >> 23) & 255u);
        int dsh = 127 - ebits;
        dsh = dsh > 126 ? 126 : (dsh < -126 ? -126 : dsh);
        float sf = exp2i(dsh);
        E += dsh;
        float2v sf2; sf2.x = sf; sf2.y = sf;
        #pragma unroll
        for (int k = 0; k < 4; ++k) P[k] = pk_mul(P[k], sf2);
        aT *= sf; aT2 *= sf;
        c7w *= sf; c7E += dsh;
    }

    float dtwv = 0.0f;
    if (lane == 63) {
        float u = (float)c7E - __builtin_amdgcn_logf(c7w);  // v_log = log2
        dtwv = fabsf(u) * (1.0f / KSC);                     // |R(511,511)|
    }

    // ---- init-free cross-block finalize (flag protocol; verified R12/R15/R17) ----
    float* slot = ws + 8 * b;
    if (lane == 63) slot[3] = dtwv;
    if (lane == 0) { slot[0] = sab; slot[1] = ssq; slot[2] = corr; }
    __syncthreads();
    __threadfence();
    if (lane == 0) atomicExch((int*)(slot + 4), MAGICF);   // release-publish

    if (b == NB - 1) {
        float m = 0.f, s = 0.f, p = 0.f, d = 0.f;
        if (lane < NB) {
            int* fl = (int*)(ws + 8 * lane + 4);
            while (atomicAdd(fl, 0) != MAGICF) { }         // acquire-spin
            __threadfence();
            float* sl = ws + 8 * lane;
            m = atomicAdd(&sl[0], 0.0f);
            s = atomicAdd(&sl[1], 0.0f);
            p = atomicAdd(&sl[2], 0.0f);
            d = atomicAdd(&sl[3], 0.0f);
        }
        #pragma unroll
        for (int mm = 1; mm < 64; mm <<= 1) {
            m += __shfl_xor(m, mm, 64);
            s += __shfl_xor(s, mm, 64);
            p += __shfl_xor(p, mm, 64);
            d += __shfl_xor(d, mm, 64);
        }
        if (lane == 0) {
            out[NB * TT + 0] = m;                         // mae_loss
            out[NB * TT + 1] = 1.0f - p * (1.0f / 32.0f); // pcc_loss
            out[NB * TT + 2] = d * (1.0f / 32.0f);        // dtw_loss
            out[NB * TT + 3] = sqrtf(s);                  // rmse_loss
        }
    }
}

extern "C" void kernel_launch(void* const* d_in, const int* in_sizes, int n_in,
                              void* d_out, int out_size, void* d_ws, size_t ws_size,
                              hipStream_t stream) {
    const float* pred_map = (const float*)d_in[0];
    const int*   lat_idx  = (const int*)d_in[1];
    const float* omega    = (const float*)d_in[2];
    const float* omni     = (const float*)d_in[3];
    float* out = (float*)d_out;
    float* ws  = (float*)d_ws;

    fused_kernel<<<NB, 64, 0, stream>>>(pred_map, lat_idx, omega, omni, out, ws);
}